// Round 4
// baseline (393.467 us; speedup 1.0000x reference)
//
#include <hip/hip_runtime.h>
#include <hip/hip_bf16.h>

// Fused MHA block. B=4, S=2048, D=768, H=16, DH=48, causal, LayerNorm(eps=1e-3).
// FP32 harness buffers; bf16 MFMA internally (threshold is bf16-lenient, 2% rel).
//
// Pipeline:
//   1. prep     : Wt[n][k] = bf16(W[k][n])  +  Xb = bf16(x) for q,k,v.
//   2. qkv_proj : phase-interleaved MFMA GEMM with counted vmcnt (T3+T4+T5).
//   3. attn     : MFMA flash attn, operand-swapped, register-resident P.
//                 R4: hot loop fully scalarized — NO unions / NO indexed
//                 aggregates (R3's unions went to scratch: 382MB WRITE_SIZE).
//                 bf16 packing via __builtin_bit_cast bit ops only.
//   4. lnorm    : vectorized LayerNorm, fp32 out.

#define DMODEL 768
#define NHEAD  16
#define DHEAD  48
#define SEQ    2048
#define NBATCH 4
#define NROWS  (NBATCH * SEQ)                 // 8192
// Q prescale: 1/sqrt(48) * log2(e)  -> softmax = single v_exp_f32 (2^x)
#define QSCALE (0.14433756729740643f * 1.4426950408889634f)

typedef __bf16 bf16x8 __attribute__((ext_vector_type(8)));
typedef float  f32x4  __attribute__((ext_vector_type(4)));
typedef unsigned int u32x4 __attribute__((ext_vector_type(4)));

static __device__ __forceinline__ unsigned int pk2(float lo, float hi) {
    unsigned short a = __builtin_bit_cast(unsigned short, (__bf16)lo);
    unsigned short b = __builtin_bit_cast(unsigned short, (__bf16)hi);
    return ((unsigned int)b << 16) | a;
}

// ---------------- 1. prep: W transpose+cvt, X cvt ----------------
__global__ __launch_bounds__(256) void prep(
    const float* __restrict__ Wq,
    const float* __restrict__ Wk,
    const float* __restrict__ Wv,
    const float* __restrict__ xq,
    const float* __restrict__ xk,
    const float* __restrict__ xv,
    __hip_bfloat16* __restrict__ Wt,
    __hip_bfloat16* __restrict__ Xbq,
    __hip_bfloat16* __restrict__ Xbk,
    __hip_bfloat16* __restrict__ Xbv)
{
    int bid = blockIdx.x;
    if (bid < 1728) {
        __shared__ __hip_bfloat16 tile[32][33];
        int mat = bid / 576;
        int t   = bid - mat * 576;
        int tr  = t / 24, tc = t - (t / 24) * 24;
        const float* W = (mat == 0) ? Wq : (mat == 1) ? Wk : Wv;
        __hip_bfloat16* O = Wt + (size_t)mat * DMODEL * DMODEL;
        int tx = threadIdx.x & 31, ty = threadIdx.x >> 5;
#pragma unroll
        for (int i = 0; i < 32; i += 8)
            tile[ty + i][tx] = __float2bfloat16(W[(size_t)(tr * 32 + ty + i) * DMODEL + tc * 32 + tx]);
        __syncthreads();
#pragma unroll
        for (int i = 0; i < 32; i += 8)
            O[(size_t)(tc * 32 + ty + i) * DMODEL + tr * 32 + tx] = tile[tx][ty + i];
    } else {
        int b2  = bid - 1728;                 // 0..9215
        int mat = b2 / 3072;
        int r   = b2 - mat * 3072;
        const float* X = (mat == 0) ? xq : (mat == 1) ? xk : xv;
        __hip_bfloat16* O = (mat == 0) ? Xbq : (mat == 1) ? Xbk : Xbv;
        size_t off = (size_t)r * 2048 + threadIdx.x * 8;
        float4 f0 = *(const float4*)(X + off);
        float4 f1 = *(const float4*)(X + off + 4);
        unsigned int w0 = pk2(f0.x, f0.y), w1 = pk2(f0.z, f0.w);
        unsigned int w2 = pk2(f1.x, f1.y), w3 = pk2(f1.z, f1.w);
        u32x4 pv; pv[0] = w0; pv[1] = w1; pv[2] = w2; pv[3] = w3;
        *(u32x4*)(O + off) = pv;
    }
}

// ---------------- 2. QKV projection: phase-interleaved, counted vmcnt --------
__global__ __launch_bounds__(512, 4) void qkv_proj(
    const __hip_bfloat16* __restrict__ Xbq,
    const __hip_bfloat16* __restrict__ Xbk,
    const __hip_bfloat16* __restrict__ Xbv,
    const __hip_bfloat16* __restrict__ Wt,
    const float* __restrict__ bq,
    const float* __restrict__ bk,
    const float* __restrict__ bv,
    __hip_bfloat16* __restrict__ Qr,
    __hip_bfloat16* __restrict__ Kr,
    __hip_bfloat16* __restrict__ Vt)
{
    __shared__ __hip_bfloat16 Abuf[3][8192];   // 3 x 16 KiB
    __shared__ __hip_bfloat16 Bbuf[2][4096];   // 2 x  8 KiB   (total 64 KiB)

    int tid  = threadIdx.x;
    int w    = tid >> 6, lane = tid & 63;
    int l16  = lane & 15, quad = lane >> 4;
    int wm   = w >> 1, wn = w & 1;             // 4M x 2N waves

    int xcd = blockIdx.x & 7, s = blockIdx.x >> 3;
    int nt  = s % 6;
    int idx = (s / 6) * 8 + xcd;               // 0..95
    int mat = idx >> 5, mt = idx & 31;
    int m0  = mt * 256, n0 = nt * 128;

    const __hip_bfloat16* X = (mat == 0) ? Xbq : (mat == 1) ? Xbk : Xbv;
    const __hip_bfloat16* W = Wt + (size_t)mat * DMODEL * DMODEL;
    const float* bias       = (mat == 0) ? bq : (mat == 1) ? bk : bv;

    int sr = tid >> 2, sc = (tid & 3) * 8;
    const __hip_bfloat16* ga0 = X + (size_t)(m0 + sr) * DMODEL + sc;
    const __hip_bfloat16* ga1 = X + (size_t)(m0 + 128 + sr) * DMODEL + sc;
    const __hip_bfloat16* gb  = W + (size_t)(n0 + sr) * DMODEL + sc;

#define GLD(gp_, lp_) __builtin_amdgcn_global_load_lds(                        \
        (const __attribute__((address_space(1))) void*)(gp_),                  \
        (__attribute__((address_space(3))) void*)(lp_), 16, 0, 0)

    int aoff = (wm * 64 + l16) * 32 + quad * 8;
    int boff = (wn * 64 + l16) * 32 + quad * 8;

    f32x4 acc[4][4] = {};

    GLD(gb,       &Bbuf[0][tid * 8]);
    GLD(ga0,      &Abuf[0][tid * 8]);
    GLD(ga1,      &Abuf[0][4096 + tid * 8]);
    GLD(ga0 + 32, &Abuf[1][tid * 8]);
    GLD(ga1 + 32, &Abuf[1][4096 + tid * 8]);
    asm volatile("s_waitcnt vmcnt(2)" ::: "memory");
    asm volatile("s_barrier" ::: "memory");

    int abuf = 0, bbuf = 0, abS = 2;
    const __hip_bfloat16* gbS  = gb  + 32;
    const __hip_bfloat16* ga0S = ga0 + 64;
    const __hip_bfloat16* ga1S = ga1 + 64;

    for (int kt = 0; kt < 24; ++kt) {
        const __hip_bfloat16* LA = Abuf[abuf];
        const __hip_bfloat16* LB = Bbuf[bbuf];

        bf16x8 a[4], bA[2];
#pragma unroll
        for (int m_ = 0; m_ < 4; ++m_)
            a[m_] = *(const bf16x8*)&LA[aoff + m_ * 512];
        bA[0] = *(const bf16x8*)&LB[boff];
        bA[1] = *(const bf16x8*)&LB[boff + 512];

        if (kt < 23) { GLD(gbS, &Bbuf[bbuf ^ 1][tid * 8]); gbS += 32; }
        if (kt < 22) {
            GLD(ga0S, &Abuf[abS][tid * 8]);
            GLD(ga1S, &Abuf[abS][4096 + tid * 8]);
            ga0S += 32; ga1S += 32;
        }

        asm volatile("s_barrier" ::: "memory");
        __builtin_amdgcn_s_setprio(1);
#pragma unroll
        for (int m_ = 0; m_ < 4; ++m_) {
            acc[m_][0] = __builtin_amdgcn_mfma_f32_16x16x32_bf16(a[m_], bA[0], acc[m_][0], 0, 0, 0);
            acc[m_][1] = __builtin_amdgcn_mfma_f32_16x16x32_bf16(a[m_], bA[1], acc[m_][1], 0, 0, 0);
        }
        __builtin_amdgcn_s_setprio(0);
        asm volatile("s_barrier" ::: "memory");

        bf16x8 bB[2];
        bB[0] = *(const bf16x8*)&LB[boff + 1024];
        bB[1] = *(const bf16x8*)&LB[boff + 1536];

        if (kt < 22) asm volatile("s_waitcnt vmcnt(2)" ::: "memory");
        else         asm volatile("s_waitcnt vmcnt(0)" ::: "memory");
        asm volatile("s_barrier" ::: "memory");
        __builtin_amdgcn_s_setprio(1);
#pragma unroll
        for (int m_ = 0; m_ < 4; ++m_) {
            acc[m_][2] = __builtin_amdgcn_mfma_f32_16x16x32_bf16(a[m_], bB[0], acc[m_][2], 0, 0, 0);
            acc[m_][3] = __builtin_amdgcn_mfma_f32_16x16x32_bf16(a[m_], bB[1], acc[m_][3], 0, 0, 0);
        }
        __builtin_amdgcn_s_setprio(0);
        asm volatile("s_barrier" ::: "memory");

        abuf = (abuf == 2) ? 0 : abuf + 1;
        abS  = (abS  == 2) ? 0 : abS  + 1;
        bbuf ^= 1;
    }
#undef GLD

    // epilogue
#pragma unroll
    for (int j = 0; j < 4; ++j) {
        int col = n0 + wn * 64 + j * 16 + l16;
        float bc = bias[col];
        if (mat == 0) {
#pragma unroll
            for (int i = 0; i < 4; ++i) {
                int row0 = m0 + wm * 64 + i * 16 + quad * 4;
#pragma unroll
                for (int r = 0; r < 4; ++r)
                    Qr[(size_t)(row0 + r) * DMODEL + col] =
                        __float2bfloat16((acc[i][j][r] + bc) * QSCALE);
            }
        } else if (mat == 1) {
#pragma unroll
            for (int i = 0; i < 4; ++i) {
                int row0 = m0 + wm * 64 + i * 16 + quad * 4;
#pragma unroll
                for (int r = 0; r < 4; ++r)
                    Kr[(size_t)(row0 + r) * DMODEL + col] =
                        __float2bfloat16(acc[i][j][r] + bc);
            }
        } else {
            int h = col / 48, dh = col - h * 48;
#pragma unroll
            for (int i = 0; i < 4; ++i) {
                int row0 = m0 + wm * 64 + i * 16 + quad * 4;
                int bb = row0 >> 11, s0 = row0 & 2047;
                unsigned int lo = pk2(acc[i][j][0] + bc, acc[i][j][1] + bc);
                unsigned int hi = pk2(acc[i][j][2] + bc, acc[i][j][3] + bc);
                uint2 pw; pw.x = lo; pw.y = hi;
                *(uint2*)(Vt + ((size_t)(bb * NHEAD + h) * DHEAD + dh) * SEQ + s0) = pw;
            }
        }
    }
}

// ---------------- 3. MFMA causal flash attention, register-resident P ------------
// K tile: Ks[buf][64][64] (cols 48..63 zero), V^T tile: Vs[buf][48][64].
// 16B-slot XOR swizzle (slot ^= row&7) on BOTH store and read.
// P never touches LDS: 2-stage shfl_xor butterfly remaps QK^T output regs
// into the PV A-frag layout. Hot loop is fully scalarized (no unions /
// indexed aggregates -> no scratch).
__global__ __launch_bounds__(256, 4) void attn(
    const __hip_bfloat16* __restrict__ Qr,
    const __hip_bfloat16* __restrict__ Kr,
    const __hip_bfloat16* __restrict__ Vt,
    __hip_bfloat16* __restrict__ Ao)
{
    __shared__ __hip_bfloat16 Ks[2][64][64];   // 16 KiB
    __shared__ __hip_bfloat16 Vs[2][48][64];   // 12 KiB  (total 28 KiB)

    int tid  = threadIdx.x;
    int w    = tid >> 6, lane = tid & 63;
    int l16  = lane & 15, quad = lane >> 4;
    bool b1  = (quad & 2) != 0, b0 = (quad & 1) != 0;
    int bh   = blockIdx.x & 63;
    int qt   = 15 - (blockIdx.x >> 6);         // heavy q-tiles dispatch first
    int q0   = qt * 128;
    int b    = bh >> 4, h = bh & 15;
    size_t rowbase = (size_t)b * SEQ;

    const __hip_bfloat16* Qp = Qr + rowbase * DMODEL + h * DHEAD;
    const __hip_bfloat16* Kp = Kr + rowbase * DMODEL + h * DHEAD;
    const __hip_bfloat16* Vp = Vt + (size_t)bh * DHEAD * SEQ;

    // zero the swizzled pad slots (logical cols 48..63) of both K buffers
    {
        int zbuf = tid >> 7, zr = (tid >> 1) & 63, zsl = 6 + (tid & 1);
        *(uint4*)&Ks[zbuf][zr][(zsl ^ (zr & 7)) * 8] = (uint4){0u, 0u, 0u, 0u};
    }

    bf16x8 bQ0[2], bQ1[2];
#pragma unroll
    for (int i = 0; i < 2; ++i) {
        int qrow = q0 + w * 32 + i * 16 + l16;
        bQ0[i] = *(const bf16x8*)(Qp + (size_t)qrow * DMODEL + quad * 8);
        bQ1[i] = (bf16x8){};
        if (quad < 2)
            bQ1[i] = *(const bf16x8*)(Qp + (size_t)qrow * DMODEL + 32 + quad * 8);
    }

    int kr1 = tid / 6,          ksl1 = tid - kr1 * 6;
    int kr2 = (tid + 256) / 6,  ksl2 = (tid + 256) - kr2 * 6;
    int vd1 = tid >> 3,         vsl1 = tid & 7;
    int vd2 = (tid + 256) >> 3, vsl2 = tid & 7;
    int kso1 = (ksl1 ^ (kr1 & 7)) * 8;
    int kso2 = (ksl2 ^ (kr2 & 7)) * 8;
    int vso1 = (vsl1 ^ (vd1 & 7)) * 8;
    int vso2 = (vsl2 ^ (vd2 & 7)) * 8;

    uint4 kv1, kv2, vv1, vv2;

#define ATTN_LOAD(kt_) {                                                        \
        int k0_ = (kt_) * 64;                                                   \
        kv1 = *(const uint4*)(Kp + (size_t)(k0_ + kr1) * DMODEL + ksl1 * 8);    \
        vv1 = *(const uint4*)(Vp + (size_t)vd1 * SEQ + k0_ + vsl1 * 8);         \
        if (tid < 128) {                                                        \
            kv2 = *(const uint4*)(Kp + (size_t)(k0_ + kr2) * DMODEL + ksl2 * 8);\
            vv2 = *(const uint4*)(Vp + (size_t)vd2 * SEQ + k0_ + vsl2 * 8);     \
        } }

#define ATTN_STORE(buf_) {                                                      \
        *(uint4*)&Ks[buf_][kr1][kso1] = kv1;                                    \
        *(uint4*)&Vs[buf_][vd1][vso1] = vv1;                                    \
        if (tid < 128) {                                                        \
            *(uint4*)&Ks[buf_][kr2][kso2] = kv2;                                \
            *(uint4*)&Vs[buf_][vd2][vso2] = vv2;                                \
        } }

    f32x4 O[2][3] = {};
    float lsum[2] = {0.f, 0.f};
    const f32x4 zf = {};

    int sA0 = (quad ^ (l16 & 7)) * 8;          // k-cols  0..31
    int sA1 = ((quad + 4) ^ (l16 & 7)) * 8;    // k-cols 32..63

    int ktmax = 2 * qt + 1;
    ATTN_LOAD(0);
    ATTN_STORE(0);
    if (ktmax >= 1) ATTN_LOAD(1);
    __syncthreads();

    for (int kt = 0; kt <= ktmax; ++kt) {
        int buf = kt & 1;
        int k0  = kt * 64;
        if (kt + 1 <= ktmax) ATTN_STORE(buf ^ 1);
        if (kt + 2 <= ktmax) ATTN_LOAD(kt + 2);

        bf16x8 aK0[4], aK1[4];
#pragma unroll
        for (int t = 0; t < 4; ++t) {
            aK0[t] = *(const bf16x8*)&Ks[buf][16 * t + l16][sA0];
            aK1[t] = *(const bf16x8*)&Ks[buf][16 * t + l16][sA1];
        }
        bf16x8 bV0[3], bV1[3];
#pragma unroll
        for (int dt = 0; dt < 3; ++dt) {
            bV0[dt] = *(const bf16x8*)&Vs[buf][dt * 16 + l16][sA0];
            bV1[dt] = *(const bf16x8*)&Vs[buf][dt * 16 + l16][sA1];
        }

#pragma unroll
        for (int i = 0; i < 2; ++i) {
            int qbase = q0 + w * 32 + i * 16;
            if (k0 > qbase + 15) continue;     // wave-uniform skip

            f32x4 s0_, s1_, s2_, s3_;
            __builtin_amdgcn_s_setprio(1);
            {
                f32x4 z;
                z   = __builtin_amdgcn_mfma_f32_16x16x32_bf16(aK0[0], bQ0[i], zf, 0, 0, 0);
                s0_ = __builtin_amdgcn_mfma_f32_16x16x32_bf16(aK1[0], bQ1[i], z,  0, 0, 0);
                z   = __builtin_amdgcn_mfma_f32_16x16x32_bf16(aK0[1], bQ0[i], zf, 0, 0, 0);
                s1_ = __builtin_amdgcn_mfma_f32_16x16x32_bf16(aK1[1], bQ1[i], z,  0, 0, 0);
                z   = __builtin_amdgcn_mfma_f32_16x16x32_bf16(aK0[2], bQ0[i], zf, 0, 0, 0);
                s2_ = __builtin_amdgcn_mfma_f32_16x16x32_bf16(aK1[2], bQ1[i], z,  0, 0, 0);
                z   = __builtin_amdgcn_mfma_f32_16x16x32_bf16(aK0[3], bQ0[i], zf, 0, 0, 0);
                s3_ = __builtin_amdgcn_mfma_f32_16x16x32_bf16(aK1[3], bQ1[i], z,  0, 0, 0);
            }
            __builtin_amdgcn_s_setprio(0);

            if (k0 + 63 > qbase) {
                int qg = qbase + l16;
#pragma unroll
                for (int r = 0; r < 4; ++r) {
                    if (k0 +  0 + quad * 4 + r > qg) s0_[r] = -1e30f;
                    if (k0 + 16 + quad * 4 + r > qg) s1_[r] = -1e30f;
                    if (k0 + 32 + quad * 4 + r > qg) s2_[r] = -1e30f;
                    if (k0 + 48 + quad * 4 + r > qg) s3_[r] = -1e30f;
                }
            }

            // exp2 + pack (scalar, bit-ops only)
            float ls = 0.f;
            unsigned int u00, u01, u10, u11, u20, u21, u30, u31;
            {
                float p0 = exp2f(s0_[0]), p1 = exp2f(s0_[1]);
                float p2 = exp2f(s0_[2]), p3 = exp2f(s0_[3]);
                ls += (p0 + p1) + (p2 + p3);
                u00 = pk2(p0, p1); u01 = pk2(p2, p3);
            }
            {
                float p0 = exp2f(s1_[0]), p1 = exp2f(s1_[1]);
                float p2 = exp2f(s1_[2]), p3 = exp2f(s1_[3]);
                ls += (p0 + p1) + (p2 + p3);
                u10 = pk2(p0, p1); u11 = pk2(p2, p3);
            }
            {
                float p0 = exp2f(s2_[0]), p1 = exp2f(s2_[1]);
                float p2 = exp2f(s2_[2]), p3 = exp2f(s2_[3]);
                ls += (p0 + p1) + (p2 + p3);
                u20 = pk2(p0, p1); u21 = pk2(p2, p3);
            }
            {
                float p0 = exp2f(s3_[0]), p1 = exp2f(s3_[1]);
                float p2 = exp2f(s3_[2]), p3 = exp2f(s3_[3]);
                ls += (p0 + p1) + (p2 + p3);
                u30 = pk2(p0, p1); u31 = pk2(p2, p3);
            }
            lsum[i] += ls;

            // stage 1 (xor 32)
            unsigned int rA0 = __shfl_xor(b1 ? u00 : u10, 32, 64);
            unsigned int rA1 = __shfl_xor(b1 ? u01 : u11, 32, 64);
            unsigned int rB0 = __shfl_xor(b1 ? u20 : u30, 32, 64);
            unsigned int rB1 = __shfl_xor(b1 ? u21 : u31, 32, 64);
            unsigned int X00 = b1 ? rA0 : u00, X01 = b1 ? rA1 : u01;
            unsigned int X10 = b1 ? u10 : rA0, X11 = b1 ? u11 : rA1;
            unsigned int X20 = b1 ? rB0 : u20, X21 = b1 ? rB1 : u21;
            unsigned int X30 = b1 ? u30 : rB0, X31 = b1 ? u31 : rB1;
            // stage 2 (xor 16)
            unsigned int rC0 = __shfl_xor(b0 ? X00 : X10, 16, 64);
            unsigned int rC1 = __shfl_xor(b0 ? X01 : X11, 16, 64);
            unsigned int rD0 = __shfl_xor(b0 ? X20 : X30, 16, 64);
            unsigned int rD1 = __shfl_xor(b0 ? X21 : X31, 16, 64);

            u32x4 P0w, P1w;
            P0w[0] = b0 ? rC0 : X00;  P0w[1] = b0 ? rC1 : X01;
            P0w[2] = b0 ? X10 : rC0;  P0w[3] = b0 ? X11 : rC1;
            P1w[0] = b0 ? rD0 : X20;  P1w[1] = b0 ? rD1 : X21;
            P1w[2] = b0 ? X30 : rD0;  P1w[3] = b0 ? X31 : rD1;
            bf16x8 P0v = __builtin_bit_cast(bf16x8, P0w);
            bf16x8 P1v = __builtin_bit_cast(bf16x8, P1w);

            __builtin_amdgcn_s_setprio(1);
#pragma unroll
            for (int dt = 0; dt < 3; ++dt) {
                O[i][dt] = __builtin_amdgcn_mfma_f32_16x16x32_bf16(P0v, bV0[dt], O[i][dt], 0, 0, 0);
                O[i][dt] = __builtin_amdgcn_mfma_f32_16x16x32_bf16(P1v, bV1[dt], O[i][dt], 0, 0, 0);
            }
            __builtin_amdgcn_s_setprio(0);
        }

        asm volatile("s_waitcnt lgkmcnt(0)" ::: "memory");
        __builtin_amdgcn_s_barrier();
        asm volatile("" ::: "memory");
    }

#pragma unroll
    for (int i = 0; i < 2; ++i) {
        lsum[i] += __shfl_xor(lsum[i], 16, 64);
        lsum[i] += __shfl_xor(lsum[i], 32, 64);
    }

#pragma unroll
    for (int i = 0; i < 2; ++i) {
#pragma unroll
        for (int r = 0; r < 4; ++r) {
            float linv = 1.f / __shfl(lsum[i], quad * 4 + r, 64);
            size_t g = (rowbase + q0 + w * 32 + i * 16 + quad * 4 + r) * DMODEL + h * DHEAD + l16;
            Ao[g + 0]  = __float2bfloat16(O[i][0][r] * linv);
            Ao[g + 16] = __float2bfloat16(O[i][1][r] * linv);
            Ao[g + 32] = __float2bfloat16(O[i][2][r] * linv);
        }
    }
#undef ATTN_LOAD
#undef ATTN_STORE
}

// ---------------- 4. LayerNorm (eps = 1e-3), vectorized, fp32 out ----------------
__global__ __launch_bounds__(192) void lnorm(
    const __hip_bfloat16* __restrict__ Ao,
    const float* __restrict__ gamma,
    const float* __restrict__ beta,
    float* __restrict__ out)
{
    __shared__ float rs_[3], rq_[3];
    int row = blockIdx.x;
    int t   = threadIdx.x;
    size_t base = (size_t)row * DMODEL + t * 4;

    ushort4 u = *(const ushort4*)(Ao + base);
    float x0, x1, x2, x3;
    { unsigned int v = (unsigned int)u.x << 16; __builtin_memcpy(&x0, &v, 4); }
    { unsigned int v = (unsigned int)u.y << 16; __builtin_memcpy(&x1, &v, 4); }
    { unsigned int v = (unsigned int)u.z << 16; __builtin_memcpy(&x2, &v, 4); }
    { unsigned int v = (unsigned int)u.w << 16; __builtin_memcpy(&x3, &v, 4); }

    float s = x0 + x1 + x2 + x3;
    float q = x0 * x0 + x1 * x1 + x2 * x2 + x3 * x3;
#pragma unroll
    for (int m = 32; m >= 1; m >>= 1) {
        s += __shfl_xor(s, m, 64);
        q += __shfl_xor(q, m, 64);
    }
    int wv = t >> 6;
    if ((t & 63) == 0) { rs_[wv] = s; rq_[wv] = q; }
    __syncthreads();
    float ts = rs_[0] + rs_[1] + rs_[2];
    float tq = rq_[0] + rq_[1] + rq_[2];
    float mu  = ts * (1.f / 768.f);
    float var = tq * (1.f / 768.f) - mu * mu;
    float rstd = rsqrtf(var + 1e-3f);

    float4 g  = *(const float4*)(gamma + t * 4);
    float4 be = *(const float4*)(beta + t * 4);
    float4 o;
    o.x = (x0 - mu) * rstd * g.x + be.x;
    o.y = (x1 - mu) * rstd * g.y + be.y;
    o.z = (x2 - mu) * rstd * g.z + be.z;
    o.w = (x3 - mu) * rstd * g.w + be.w;
    *(float4*)(out + base) = o;
}

extern "C" void kernel_launch(void* const* d_in, const int* in_sizes, int n_in,
                              void* d_out, int out_size, void* d_ws, size_t ws_size,
                              hipStream_t stream) {
    const float* q     = (const float*)d_in[0];
    const float* k     = (const float*)d_in[1];
    const float* v     = (const float*)d_in[2];
    const float* Wq    = (const float*)d_in[3];
    const float* bq    = (const float*)d_in[4];
    const float* Wk    = (const float*)d_in[5];
    const float* bk    = (const float*)d_in[6];
    const float* Wv    = (const float*)d_in[7];
    const float* bv    = (const float*)d_in[8];
    const float* gamma = (const float*)d_in[9];
    const float* beta  = (const float*)d_in[10];

    char* basep = (char*)d_ws;
    __hip_bfloat16* Wt = (__hip_bfloat16*)basep;
    __hip_bfloat16* Qr = (__hip_bfloat16*)(basep + 3538944);
    __hip_bfloat16* Kr = Qr + (size_t)NROWS * DMODEL;
    __hip_bfloat16* Vt = Kr + (size_t)NROWS * DMODEL;
    __hip_bfloat16* Ao = Vt + (size_t)NROWS * DMODEL;
    float* out = (float*)d_out;

    __hip_bfloat16* Xbq = (__hip_bfloat16*)d_out;
    __hip_bfloat16* Xbk = Xbq + (size_t)NROWS * DMODEL;
    __hip_bfloat16* Xbv = Ao;

    hipLaunchKernelGGL(prep, dim3(10944), dim3(256), 0, stream,
                       Wq, Wk, Wv, q, k, v, Wt, Xbq, Xbk, Xbv);
    hipLaunchKernelGGL(qkv_proj, dim3(576), dim3(512), 0, stream,
                       Xbq, Xbk, Xbv, Wt, bq, bk, bv, Qr, Kr, Vt);
    hipLaunchKernelGGL(attn, dim3(1024), dim3(256), 0, stream, Qr, Kr, Vt, Ao);
    hipLaunchKernelGGL(lnorm, dim3(8192), dim3(192), 0, stream, Ao, gamma, beta, out);
}

// Round 5
// 270.416 us; speedup vs baseline: 1.4550x; 1.4550x over previous
//
#include <hip/hip_runtime.h>
#include <hip/hip_bf16.h>

// Fused MHA block. B=4, S=2048, D=768, H=16, DH=48, causal, LayerNorm(eps=1e-3).
// FP32 harness buffers; bf16 MFMA internally (threshold is bf16-lenient, 2% rel).
//
// Pipeline:
//   1. prep     : Wt[n][k] = bf16(W[k][n])  +  Xb = bf16(x) for q,k,v.
//   2. qkv_proj : phase-interleaved MFMA GEMM with counted vmcnt (T3+T4+T5).
//   3. attn     : MFMA flash attn, operand-swapped, register-resident P.
//                 R5: phase-disjoint register schedule (QK -> softmax -> PV) so
//                 peak pressure ~140 regs; __launch_bounds__(256,3) caps at
//                 ~170 (R3/R4 spilled ~370MB scratch under the 128 cap of
//                 (256,4) — WRITE_SIZE 383MB, VGPR=64+64unified).
//   4. lnorm    : wave-per-row LayerNorm, no LDS/syncthreads, fp32 out.

#define DMODEL 768
#define NHEAD  16
#define DHEAD  48
#define SEQ    2048
#define NBATCH 4
#define NROWS  (NBATCH * SEQ)                 // 8192
// Q prescale: 1/sqrt(48) * log2(e)  -> softmax = single v_exp_f32 (2^x)
#define QSCALE (0.14433756729740643f * 1.4426950408889634f)

typedef __bf16 bf16x8 __attribute__((ext_vector_type(8)));
typedef float  f32x4  __attribute__((ext_vector_type(4)));
typedef unsigned int u32x4 __attribute__((ext_vector_type(4)));

static __device__ __forceinline__ unsigned int pk2(float lo, float hi) {
    unsigned short a = __builtin_bit_cast(unsigned short, (__bf16)lo);
    unsigned short b = __builtin_bit_cast(unsigned short, (__bf16)hi);
    return ((unsigned int)b << 16) | a;
}

// ---------------- 1. prep: W transpose+cvt, X cvt ----------------
__global__ __launch_bounds__(256) void prep(
    const float* __restrict__ Wq,
    const float* __restrict__ Wk,
    const float* __restrict__ Wv,
    const float* __restrict__ xq,
    const float* __restrict__ xk,
    const float* __restrict__ xv,
    __hip_bfloat16* __restrict__ Wt,
    __hip_bfloat16* __restrict__ Xbq,
    __hip_bfloat16* __restrict__ Xbk,
    __hip_bfloat16* __restrict__ Xbv)
{
    int bid = blockIdx.x;
    if (bid < 1728) {
        __shared__ __hip_bfloat16 tile[32][33];
        int mat = bid / 576;
        int t   = bid - mat * 576;
        int tr  = t / 24, tc = t - (t / 24) * 24;
        const float* W = (mat == 0) ? Wq : (mat == 1) ? Wk : Wv;
        __hip_bfloat16* O = Wt + (size_t)mat * DMODEL * DMODEL;
        int tx = threadIdx.x & 31, ty = threadIdx.x >> 5;
#pragma unroll
        for (int i = 0; i < 32; i += 8)
            tile[ty + i][tx] = __float2bfloat16(W[(size_t)(tr * 32 + ty + i) * DMODEL + tc * 32 + tx]);
        __syncthreads();
#pragma unroll
        for (int i = 0; i < 32; i += 8)
            O[(size_t)(tc * 32 + ty + i) * DMODEL + tr * 32 + tx] = tile[tx][ty + i];
    } else {
        int b2  = bid - 1728;                 // 0..9215
        int mat = b2 / 3072;
        int r   = b2 - mat * 3072;
        const float* X = (mat == 0) ? xq : (mat == 1) ? xk : xv;
        __hip_bfloat16* O = (mat == 0) ? Xbq : (mat == 1) ? Xbk : Xbv;
        size_t off = (size_t)r * 2048 + threadIdx.x * 8;
        float4 f0 = *(const float4*)(X + off);
        float4 f1 = *(const float4*)(X + off + 4);
        unsigned int w0 = pk2(f0.x, f0.y), w1 = pk2(f0.z, f0.w);
        unsigned int w2 = pk2(f1.x, f1.y), w3 = pk2(f1.z, f1.w);
        u32x4 pv; pv[0] = w0; pv[1] = w1; pv[2] = w2; pv[3] = w3;
        *(u32x4*)(O + off) = pv;
    }
}

// ---------------- 2. QKV projection: phase-interleaved, counted vmcnt --------
__global__ __launch_bounds__(512, 4) void qkv_proj(
    const __hip_bfloat16* __restrict__ Xbq,
    const __hip_bfloat16* __restrict__ Xbk,
    const __hip_bfloat16* __restrict__ Xbv,
    const __hip_bfloat16* __restrict__ Wt,
    const float* __restrict__ bq,
    const float* __restrict__ bk,
    const float* __restrict__ bv,
    __hip_bfloat16* __restrict__ Qr,
    __hip_bfloat16* __restrict__ Kr,
    __hip_bfloat16* __restrict__ Vt)
{
    __shared__ __hip_bfloat16 Abuf[3][8192];   // 3 x 16 KiB
    __shared__ __hip_bfloat16 Bbuf[2][4096];   // 2 x  8 KiB   (total 64 KiB)

    int tid  = threadIdx.x;
    int w    = tid >> 6, lane = tid & 63;
    int l16  = lane & 15, quad = lane >> 4;
    int wm   = w >> 1, wn = w & 1;             // 4M x 2N waves

    int xcd = blockIdx.x & 7, s = blockIdx.x >> 3;
    int nt  = s % 6;
    int idx = (s / 6) * 8 + xcd;               // 0..95
    int mat = idx >> 5, mt = idx & 31;
    int m0  = mt * 256, n0 = nt * 128;

    const __hip_bfloat16* X = (mat == 0) ? Xbq : (mat == 1) ? Xbk : Xbv;
    const __hip_bfloat16* W = Wt + (size_t)mat * DMODEL * DMODEL;
    const float* bias       = (mat == 0) ? bq : (mat == 1) ? bk : bv;

    int sr = tid >> 2, sc = (tid & 3) * 8;
    const __hip_bfloat16* ga0 = X + (size_t)(m0 + sr) * DMODEL + sc;
    const __hip_bfloat16* ga1 = X + (size_t)(m0 + 128 + sr) * DMODEL + sc;
    const __hip_bfloat16* gb  = W + (size_t)(n0 + sr) * DMODEL + sc;

#define GLD(gp_, lp_) __builtin_amdgcn_global_load_lds(                        \
        (const __attribute__((address_space(1))) void*)(gp_),                  \
        (__attribute__((address_space(3))) void*)(lp_), 16, 0, 0)

    int aoff = (wm * 64 + l16) * 32 + quad * 8;
    int boff = (wn * 64 + l16) * 32 + quad * 8;

    f32x4 acc[4][4] = {};

    GLD(gb,       &Bbuf[0][tid * 8]);
    GLD(ga0,      &Abuf[0][tid * 8]);
    GLD(ga1,      &Abuf[0][4096 + tid * 8]);
    GLD(ga0 + 32, &Abuf[1][tid * 8]);
    GLD(ga1 + 32, &Abuf[1][4096 + tid * 8]);
    asm volatile("s_waitcnt vmcnt(2)" ::: "memory");
    asm volatile("s_barrier" ::: "memory");

    int abuf = 0, bbuf = 0, abS = 2;
    const __hip_bfloat16* gbS  = gb  + 32;
    const __hip_bfloat16* ga0S = ga0 + 64;
    const __hip_bfloat16* ga1S = ga1 + 64;

    for (int kt = 0; kt < 24; ++kt) {
        const __hip_bfloat16* LA = Abuf[abuf];
        const __hip_bfloat16* LB = Bbuf[bbuf];

        bf16x8 a[4], bA[2];
#pragma unroll
        for (int m_ = 0; m_ < 4; ++m_)
            a[m_] = *(const bf16x8*)&LA[aoff + m_ * 512];
        bA[0] = *(const bf16x8*)&LB[boff];
        bA[1] = *(const bf16x8*)&LB[boff + 512];

        if (kt < 23) { GLD(gbS, &Bbuf[bbuf ^ 1][tid * 8]); gbS += 32; }
        if (kt < 22) {
            GLD(ga0S, &Abuf[abS][tid * 8]);
            GLD(ga1S, &Abuf[abS][4096 + tid * 8]);
            ga0S += 32; ga1S += 32;
        }

        asm volatile("s_barrier" ::: "memory");
        __builtin_amdgcn_s_setprio(1);
#pragma unroll
        for (int m_ = 0; m_ < 4; ++m_) {
            acc[m_][0] = __builtin_amdgcn_mfma_f32_16x16x32_bf16(a[m_], bA[0], acc[m_][0], 0, 0, 0);
            acc[m_][1] = __builtin_amdgcn_mfma_f32_16x16x32_bf16(a[m_], bA[1], acc[m_][1], 0, 0, 0);
        }
        __builtin_amdgcn_s_setprio(0);
        asm volatile("s_barrier" ::: "memory");

        bf16x8 bB[2];
        bB[0] = *(const bf16x8*)&LB[boff + 1024];
        bB[1] = *(const bf16x8*)&LB[boff + 1536];

        if (kt < 22) asm volatile("s_waitcnt vmcnt(2)" ::: "memory");
        else         asm volatile("s_waitcnt vmcnt(0)" ::: "memory");
        asm volatile("s_barrier" ::: "memory");
        __builtin_amdgcn_s_setprio(1);
#pragma unroll
        for (int m_ = 0; m_ < 4; ++m_) {
            acc[m_][2] = __builtin_amdgcn_mfma_f32_16x16x32_bf16(a[m_], bB[0], acc[m_][2], 0, 0, 0);
            acc[m_][3] = __builtin_amdgcn_mfma_f32_16x16x32_bf16(a[m_], bB[1], acc[m_][3], 0, 0, 0);
        }
        __builtin_amdgcn_s_setprio(0);
        asm volatile("s_barrier" ::: "memory");

        abuf = (abuf == 2) ? 0 : abuf + 1;
        abS  = (abS  == 2) ? 0 : abS  + 1;
        bbuf ^= 1;
    }
#undef GLD

    // epilogue
#pragma unroll
    for (int j = 0; j < 4; ++j) {
        int col = n0 + wn * 64 + j * 16 + l16;
        float bc = bias[col];
        if (mat == 0) {
#pragma unroll
            for (int i = 0; i < 4; ++i) {
                int row0 = m0 + wm * 64 + i * 16 + quad * 4;
#pragma unroll
                for (int r = 0; r < 4; ++r)
                    Qr[(size_t)(row0 + r) * DMODEL + col] =
                        __float2bfloat16((acc[i][j][r] + bc) * QSCALE);
            }
        } else if (mat == 1) {
#pragma unroll
            for (int i = 0; i < 4; ++i) {
                int row0 = m0 + wm * 64 + i * 16 + quad * 4;
#pragma unroll
                for (int r = 0; r < 4; ++r)
                    Kr[(size_t)(row0 + r) * DMODEL + col] =
                        __float2bfloat16(acc[i][j][r] + bc);
            }
        } else {
            int h = col / 48, dh = col - h * 48;
#pragma unroll
            for (int i = 0; i < 4; ++i) {
                int row0 = m0 + wm * 64 + i * 16 + quad * 4;
                int bb = row0 >> 11, s0 = row0 & 2047;
                unsigned int lo = pk2(acc[i][j][0] + bc, acc[i][j][1] + bc);
                unsigned int hi = pk2(acc[i][j][2] + bc, acc[i][j][3] + bc);
                uint2 pw; pw.x = lo; pw.y = hi;
                *(uint2*)(Vt + ((size_t)(bb * NHEAD + h) * DHEAD + dh) * SEQ + s0) = pw;
            }
        }
    }
}

// ---------------- 3. MFMA causal flash attention, register-resident P ------------
// Phase-disjoint schedule per k-tile: QK (aK live) -> mask/exp/pack (s live) ->
// bV load -> butterfly+PV. Peak ~140 regs; (256,3) caps at ~170 -> no spill.
__global__ __launch_bounds__(256, 3) void attn(
    const __hip_bfloat16* __restrict__ Qr,
    const __hip_bfloat16* __restrict__ Kr,
    const __hip_bfloat16* __restrict__ Vt,
    __hip_bfloat16* __restrict__ Ao)
{
    __shared__ __hip_bfloat16 Ks[2][64][64];   // 16 KiB
    __shared__ __hip_bfloat16 Vs[2][48][64];   // 12 KiB  (total 28 KiB)

    int tid  = threadIdx.x;
    int w    = tid >> 6, lane = tid & 63;
    int l16  = lane & 15, quad = lane >> 4;
    bool b1  = (quad & 2) != 0, b0 = (quad & 1) != 0;
    int bh   = blockIdx.x & 63;
    int qt   = 15 - (blockIdx.x >> 6);         // heavy q-tiles dispatch first
    int q0   = qt * 128;
    int b    = bh >> 4, h = bh & 15;
    size_t rowbase = (size_t)b * SEQ;

    const __hip_bfloat16* Qp = Qr + rowbase * DMODEL + h * DHEAD;
    const __hip_bfloat16* Kp = Kr + rowbase * DMODEL + h * DHEAD;
    const __hip_bfloat16* Vp = Vt + (size_t)bh * DHEAD * SEQ;

    // zero the swizzled pad slots (logical cols 48..63) of both K buffers
    {
        int zbuf = tid >> 7, zr = (tid >> 1) & 63, zsl = 6 + (tid & 1);
        *(uint4*)&Ks[zbuf][zr][(zsl ^ (zr & 7)) * 8] = (uint4){0u, 0u, 0u, 0u};
    }

    int qb0 = q0 + w * 32, qb1 = qb0 + 16;
    bf16x8 bQa0, bQb0, bQa1, bQb1;
    {
        int qrow0 = qb0 + l16, qrow1 = qb1 + l16;
        bQa0 = *(const bf16x8*)(Qp + (size_t)qrow0 * DMODEL + quad * 8);
        bQa1 = *(const bf16x8*)(Qp + (size_t)qrow1 * DMODEL + quad * 8);
        bQb0 = (bf16x8){};
        bQb1 = (bf16x8){};
        if (quad < 2) {
            bQb0 = *(const bf16x8*)(Qp + (size_t)qrow0 * DMODEL + 32 + quad * 8);
            bQb1 = *(const bf16x8*)(Qp + (size_t)qrow1 * DMODEL + 32 + quad * 8);
        }
    }

    int kr1 = tid / 6,          ksl1 = tid - kr1 * 6;
    int kr2 = (tid + 256) / 6,  ksl2 = (tid + 256) - kr2 * 6;
    int vd1 = tid >> 3,         vsl1 = tid & 7;
    int vd2 = (tid + 256) >> 3, vsl2 = tid & 7;
    int kso1 = (ksl1 ^ (kr1 & 7)) * 8;
    int kso2 = (ksl2 ^ (kr2 & 7)) * 8;
    int vso1 = (vsl1 ^ (vd1 & 7)) * 8;
    int vso2 = (vsl2 ^ (vd2 & 7)) * 8;

    uint4 kv1, kv2, vv1, vv2;

#define ATTN_LOAD(kt_) {                                                        \
        int k0_ = (kt_) * 64;                                                   \
        kv1 = *(const uint4*)(Kp + (size_t)(k0_ + kr1) * DMODEL + ksl1 * 8);    \
        vv1 = *(const uint4*)(Vp + (size_t)vd1 * SEQ + k0_ + vsl1 * 8);         \
        if (tid < 128) {                                                        \
            kv2 = *(const uint4*)(Kp + (size_t)(k0_ + kr2) * DMODEL + ksl2 * 8);\
            vv2 = *(const uint4*)(Vp + (size_t)vd2 * SEQ + k0_ + vsl2 * 8);     \
        } }

#define ATTN_STORE(buf_) {                                                      \
        *(uint4*)&Ks[buf_][kr1][kso1] = kv1;                                    \
        *(uint4*)&Vs[buf_][vd1][vso1] = vv1;                                    \
        if (tid < 128) {                                                        \
            *(uint4*)&Ks[buf_][kr2][kso2] = kv2;                                \
            *(uint4*)&Vs[buf_][vd2][vso2] = vv2;                                \
        } }

// exp2 + pack one f32x4 pair row -> two packed words, accumulate row sum
#define EXPPK(sv_, uo0_, uo1_, ls_) {                                          \
        float p0 = exp2f(sv_[0]), p1 = exp2f(sv_[1]);                          \
        float p2 = exp2f(sv_[2]), p3 = exp2f(sv_[3]);                          \
        ls_ += (p0 + p1) + (p2 + p3);                                          \
        uo0_ = pk2(p0, p1); uo1_ = pk2(p2, p3); }

// 2-stage shfl_xor butterfly: (u00..u31) -> PV A-frags P0v_, P1v_
#define BFLY(u00,u01,u10,u11,u20,u21,u30,u31, P0v_, P1v_) {                    \
        unsigned int rA0 = __shfl_xor(b1 ? u00 : u10, 32, 64);                 \
        unsigned int rA1 = __shfl_xor(b1 ? u01 : u11, 32, 64);                 \
        unsigned int rB0 = __shfl_xor(b1 ? u20 : u30, 32, 64);                 \
        unsigned int rB1 = __shfl_xor(b1 ? u21 : u31, 32, 64);                 \
        unsigned int X00 = b1 ? rA0 : u00, X01 = b1 ? rA1 : u01;               \
        unsigned int X10 = b1 ? u10 : rA0, X11 = b1 ? u11 : rA1;               \
        unsigned int X20 = b1 ? rB0 : u20, X21 = b1 ? rB1 : u21;               \
        unsigned int X30 = b1 ? u30 : rB0, X31 = b1 ? u31 : rB1;               \
        unsigned int rC0 = __shfl_xor(b0 ? X00 : X10, 16, 64);                 \
        unsigned int rC1 = __shfl_xor(b0 ? X01 : X11, 16, 64);                 \
        unsigned int rD0 = __shfl_xor(b0 ? X20 : X30, 16, 64);                 \
        unsigned int rD1 = __shfl_xor(b0 ? X21 : X31, 16, 64);                 \
        u32x4 P0w, P1w;                                                        \
        P0w[0] = b0 ? rC0 : X00;  P0w[1] = b0 ? rC1 : X01;                     \
        P0w[2] = b0 ? X10 : rC0;  P0w[3] = b0 ? X11 : rC1;                     \
        P1w[0] = b0 ? rD0 : X20;  P1w[1] = b0 ? rD1 : X21;                     \
        P1w[2] = b0 ? X30 : rD0;  P1w[3] = b0 ? X31 : rD1;                     \
        P0v_ = __builtin_bit_cast(bf16x8, P0w);                                \
        P1v_ = __builtin_bit_cast(bf16x8, P1w); }

#define MFMA16(A_, B_, C_) __builtin_amdgcn_mfma_f32_16x16x32_bf16(A_, B_, C_, 0, 0, 0)

    f32x4 O00 = {}, O01 = {}, O02 = {}, O10 = {}, O11 = {}, O12 = {};
    float lsum0 = 0.f, lsum1 = 0.f;
    const f32x4 zf = {};

    int sA0 = (quad ^ (l16 & 7)) * 8;          // k-cols  0..31
    int sA1 = ((quad + 4) ^ (l16 & 7)) * 8;    // k-cols 32..63

    int ktmax = 2 * qt + 1;
    ATTN_LOAD(0);
    ATTN_STORE(0);
    if (ktmax >= 1) ATTN_LOAD(1);
    __syncthreads();

    for (int kt = 0; kt <= ktmax; ++kt) {
        int buf = kt & 1;
        int k0  = kt * 64;
        if (kt + 1 <= ktmax) ATTN_STORE(buf ^ 1);
        if (kt + 2 <= ktmax) ATTN_LOAD(kt + 2);

        bool do0 = (k0 <= qb0 + 15);           // wave-uniform
        bool do1 = (k0 <= qb1 + 15);

        // ---------- phase 1: QK^T (aK live, dies here) ----------
        f32x4 sA0_, sA1_, sA2_, sA3_, sB0_, sB1_, sB2_, sB3_;
        {
            bf16x8 aK00 = *(const bf16x8*)&Ks[buf][ 0 + l16][sA0];
            bf16x8 aK01 = *(const bf16x8*)&Ks[buf][16 + l16][sA0];
            bf16x8 aK02 = *(const bf16x8*)&Ks[buf][32 + l16][sA0];
            bf16x8 aK03 = *(const bf16x8*)&Ks[buf][48 + l16][sA0];
            bf16x8 aK10 = *(const bf16x8*)&Ks[buf][ 0 + l16][sA1];
            bf16x8 aK11 = *(const bf16x8*)&Ks[buf][16 + l16][sA1];
            bf16x8 aK12 = *(const bf16x8*)&Ks[buf][32 + l16][sA1];
            bf16x8 aK13 = *(const bf16x8*)&Ks[buf][48 + l16][sA1];
            __builtin_amdgcn_s_setprio(1);
            if (do0) {
                f32x4 z;
                z = MFMA16(aK00, bQa0, zf); sA0_ = MFMA16(aK10, bQb0, z);
                z = MFMA16(aK01, bQa0, zf); sA1_ = MFMA16(aK11, bQb0, z);
                z = MFMA16(aK02, bQa0, zf); sA2_ = MFMA16(aK12, bQb0, z);
                z = MFMA16(aK03, bQa0, zf); sA3_ = MFMA16(aK13, bQb0, z);
            }
            if (do1) {
                f32x4 z;
                z = MFMA16(aK00, bQa1, zf); sB0_ = MFMA16(aK10, bQb1, z);
                z = MFMA16(aK01, bQa1, zf); sB1_ = MFMA16(aK11, bQb1, z);
                z = MFMA16(aK02, bQa1, zf); sB2_ = MFMA16(aK12, bQb1, z);
                z = MFMA16(aK03, bQa1, zf); sB3_ = MFMA16(aK13, bQb1, z);
            }
            __builtin_amdgcn_s_setprio(0);
        }

        // ---------- phase 2: causal mask + exp2 + pack (s dies here) ----------
        unsigned int a00, a01, a10, a11, a20, a21, a30, a31;
        unsigned int c00, c01, c10, c11, c20, c21, c30, c31;
        if (do0) {
            if (k0 + 63 > qb0) {
                int qg = qb0 + l16;
#pragma unroll
                for (int r = 0; r < 4; ++r) {
                    if (k0 +  0 + quad * 4 + r > qg) sA0_[r] = -1e30f;
                    if (k0 + 16 + quad * 4 + r > qg) sA1_[r] = -1e30f;
                    if (k0 + 32 + quad * 4 + r > qg) sA2_[r] = -1e30f;
                    if (k0 + 48 + quad * 4 + r > qg) sA3_[r] = -1e30f;
                }
            }
            float ls = 0.f;
            EXPPK(sA0_, a00, a01, ls);
            EXPPK(sA1_, a10, a11, ls);
            EXPPK(sA2_, a20, a21, ls);
            EXPPK(sA3_, a30, a31, ls);
            lsum0 += ls;
        }
        if (do1) {
            if (k0 + 63 > qb1) {
                int qg = qb1 + l16;
#pragma unroll
                for (int r = 0; r < 4; ++r) {
                    if (k0 +  0 + quad * 4 + r > qg) sB0_[r] = -1e30f;
                    if (k0 + 16 + quad * 4 + r > qg) sB1_[r] = -1e30f;
                    if (k0 + 32 + quad * 4 + r > qg) sB2_[r] = -1e30f;
                    if (k0 + 48 + quad * 4 + r > qg) sB3_[r] = -1e30f;
                }
            }
            float ls = 0.f;
            EXPPK(sB0_, c00, c01, ls);
            EXPPK(sB1_, c10, c11, ls);
            EXPPK(sB2_, c20, c21, ls);
            EXPPK(sB3_, c30, c31, ls);
            lsum1 += ls;
        }

        // ---------- phase 3: V frags + butterfly + PV ----------
        {
            bf16x8 bV00 = *(const bf16x8*)&Vs[buf][ 0 + l16][sA0];
            bf16x8 bV01 = *(const bf16x8*)&Vs[buf][16 + l16][sA0];
            bf16x8 bV02 = *(const bf16x8*)&Vs[buf][32 + l16][sA0];
            bf16x8 bV10 = *(const bf16x8*)&Vs[buf][ 0 + l16][sA1];
            bf16x8 bV11 = *(const bf16x8*)&Vs[buf][16 + l16][sA1];
            bf16x8 bV12 = *(const bf16x8*)&Vs[buf][32 + l16][sA1];

            if (do0) {
                bf16x8 P0v, P1v;
                BFLY(a00, a01, a10, a11, a20, a21, a30, a31, P0v, P1v);
                __builtin_amdgcn_s_setprio(1);
                O00 = MFMA16(P0v, bV00, O00); O00 = MFMA16(P1v, bV10, O00);
                O01 = MFMA16(P0v, bV01, O01); O01 = MFMA16(P1v, bV11, O01);
                O02 = MFMA16(P0v, bV02, O02); O02 = MFMA16(P1v, bV12, O02);
                __builtin_amdgcn_s_setprio(0);
            }
            if (do1) {
                bf16x8 P0v, P1v;
                BFLY(c00, c01, c10, c11, c20, c21, c30, c31, P0v, P1v);
                __builtin_amdgcn_s_setprio(1);
                O10 = MFMA16(P0v, bV00, O10); O10 = MFMA16(P1v, bV10, O10);
                O11 = MFMA16(P0v, bV01, O11); O11 = MFMA16(P1v, bV11, O11);
                O12 = MFMA16(P0v, bV02, O12); O12 = MFMA16(P1v, bV12, O12);
                __builtin_amdgcn_s_setprio(0);
            }
        }

        asm volatile("s_waitcnt lgkmcnt(0)" ::: "memory");
        __builtin_amdgcn_s_barrier();
        asm volatile("" ::: "memory");
    }

    lsum0 += __shfl_xor(lsum0, 16, 64);
    lsum0 += __shfl_xor(lsum0, 32, 64);
    lsum1 += __shfl_xor(lsum1, 16, 64);
    lsum1 += __shfl_xor(lsum1, 32, 64);

#pragma unroll
    for (int r = 0; r < 4; ++r) {
        {
            float linv = 1.f / __shfl(lsum0, quad * 4 + r, 64);
            size_t g = (rowbase + qb0 + quad * 4 + r) * DMODEL + h * DHEAD + l16;
            Ao[g + 0]  = __float2bfloat16(O00[r] * linv);
            Ao[g + 16] = __float2bfloat16(O01[r] * linv);
            Ao[g + 32] = __float2bfloat16(O02[r] * linv);
        }
        {
            float linv = 1.f / __shfl(lsum1, quad * 4 + r, 64);
            size_t g = (rowbase + qb1 + quad * 4 + r) * DMODEL + h * DHEAD + l16;
            Ao[g + 0]  = __float2bfloat16(O10[r] * linv);
            Ao[g + 16] = __float2bfloat16(O11[r] * linv);
            Ao[g + 32] = __float2bfloat16(O12[r] * linv);
        }
    }
#undef ATTN_LOAD
#undef ATTN_STORE
#undef EXPPK
#undef BFLY
#undef MFMA16
}

// ---------------- 4. LayerNorm (eps = 1e-3), wave-per-row, fp32 out ----------------
__global__ __launch_bounds__(256) void lnorm(
    const __hip_bfloat16* __restrict__ Ao,
    const float* __restrict__ gamma,
    const float* __restrict__ beta,
    float* __restrict__ out)
{
    int tid = threadIdx.x;
    int wv  = tid >> 6, ln = tid & 63;
    int row = blockIdx.x * 4 + wv;
    size_t base = (size_t)row * DMODEL + ln * 4;

    ushort4 u0 = *(const ushort4*)(Ao + base);
    ushort4 u1 = *(const ushort4*)(Ao + base + 256);
    ushort4 u2 = *(const ushort4*)(Ao + base + 512);
    float x0, x1, x2, x3, x4, x5, x6, x7, x8, x9, xa, xb;
    { unsigned int v = (unsigned int)u0.x << 16; __builtin_memcpy(&x0, &v, 4); }
    { unsigned int v = (unsigned int)u0.y << 16; __builtin_memcpy(&x1, &v, 4); }
    { unsigned int v = (unsigned int)u0.z << 16; __builtin_memcpy(&x2, &v, 4); }
    { unsigned int v = (unsigned int)u0.w << 16; __builtin_memcpy(&x3, &v, 4); }
    { unsigned int v = (unsigned int)u1.x << 16; __builtin_memcpy(&x4, &v, 4); }
    { unsigned int v = (unsigned int)u1.y << 16; __builtin_memcpy(&x5, &v, 4); }
    { unsigned int v = (unsigned int)u1.z << 16; __builtin_memcpy(&x6, &v, 4); }
    { unsigned int v = (unsigned int)u1.w << 16; __builtin_memcpy(&x7, &v, 4); }
    { unsigned int v = (unsigned int)u2.x << 16; __builtin_memcpy(&x8, &v, 4); }
    { unsigned int v = (unsigned int)u2.y << 16; __builtin_memcpy(&x9, &v, 4); }
    { unsigned int v = (unsigned int)u2.z << 16; __builtin_memcpy(&xa, &v, 4); }
    { unsigned int v = (unsigned int)u2.w << 16; __builtin_memcpy(&xb, &v, 4); }

    float s = ((x0 + x1) + (x2 + x3)) + ((x4 + x5) + (x6 + x7)) + ((x8 + x9) + (xa + xb));
    float q = ((x0*x0 + x1*x1) + (x2*x2 + x3*x3)) + ((x4*x4 + x5*x5) + (x6*x6 + x7*x7))
            + ((x8*x8 + x9*x9) + (xa*xa + xb*xb));
#pragma unroll
    for (int m = 32; m >= 1; m >>= 1) {
        s += __shfl_xor(s, m, 64);
        q += __shfl_xor(q, m, 64);
    }
    float mu  = s * (1.f / 768.f);
    float var = q * (1.f / 768.f) - mu * mu;
    float rstd = rsqrtf(var + 1e-3f);

    float4 g0 = *(const float4*)(gamma + ln * 4);
    float4 g1 = *(const float4*)(gamma + ln * 4 + 256);
    float4 g2 = *(const float4*)(gamma + ln * 4 + 512);
    float4 e0 = *(const float4*)(beta + ln * 4);
    float4 e1 = *(const float4*)(beta + ln * 4 + 256);
    float4 e2 = *(const float4*)(beta + ln * 4 + 512);
    float4 o0, o1, o2;
    o0.x = (x0 - mu) * rstd * g0.x + e0.x;
    o0.y = (x1 - mu) * rstd * g0.y + e0.y;
    o0.z = (x2 - mu) * rstd * g0.z + e0.z;
    o0.w = (x3 - mu) * rstd * g0.w + e0.w;
    o1.x = (x4 - mu) * rstd * g1.x + e1.x;
    o1.y = (x5 - mu) * rstd * g1.y + e1.y;
    o1.z = (x6 - mu) * rstd * g1.z + e1.z;
    o1.w = (x7 - mu) * rstd * g1.w + e1.w;
    o2.x = (x8 - mu) * rstd * g2.x + e2.x;
    o2.y = (x9 - mu) * rstd * g2.y + e2.y;
    o2.z = (xa - mu) * rstd * g2.z + e2.z;
    o2.w = (xb - mu) * rstd * g2.w + e2.w;
    *(float4*)(out + base)       = o0;
    *(float4*)(out + base + 256) = o1;
    *(float4*)(out + base + 512) = o2;
}

extern "C" void kernel_launch(void* const* d_in, const int* in_sizes, int n_in,
                              void* d_out, int out_size, void* d_ws, size_t ws_size,
                              hipStream_t stream) {
    const float* q     = (const float*)d_in[0];
    const float* k     = (const float*)d_in[1];
    const float* v     = (const float*)d_in[2];
    const float* Wq    = (const float*)d_in[3];
    const float* bq    = (const float*)d_in[4];
    const float* Wk    = (const float*)d_in[5];
    const float* bk    = (const float*)d_in[6];
    const float* Wv    = (const float*)d_in[7];
    const float* bv    = (const float*)d_in[8];
    const float* gamma = (const float*)d_in[9];
    const float* beta  = (const float*)d_in[10];

    char* basep = (char*)d_ws;
    __hip_bfloat16* Wt = (__hip_bfloat16*)basep;
    __hip_bfloat16* Qr = (__hip_bfloat16*)(basep + 3538944);
    __hip_bfloat16* Kr = Qr + (size_t)NROWS * DMODEL;
    __hip_bfloat16* Vt = Kr + (size_t)NROWS * DMODEL;
    __hip_bfloat16* Ao = Vt + (size_t)NROWS * DMODEL;
    float* out = (float*)d_out;

    __hip_bfloat16* Xbq = (__hip_bfloat16*)d_out;
    __hip_bfloat16* Xbk = Xbq + (size_t)NROWS * DMODEL;
    __hip_bfloat16* Xbv = Ao;

    hipLaunchKernelGGL(prep, dim3(10944), dim3(256), 0, stream,
                       Wq, Wk, Wv, q, k, v, Wt, Xbq, Xbk, Xbv);
    hipLaunchKernelGGL(qkv_proj, dim3(576), dim3(512), 0, stream,
                       Xbq, Xbk, Xbv, Wt, bq, bk, bv, Qr, Kr, Vt);
    hipLaunchKernelGGL(attn, dim3(1024), dim3(256), 0, stream, Qr, Kr, Vt, Ao);
    hipLaunchKernelGGL(lnorm, dim3(2048), dim3(256), 0, stream, Ao, gamma, beta, out);
}

// Round 6
// 260.564 us; speedup vs baseline: 1.5101x; 1.0378x over previous
//
#include <hip/hip_runtime.h>
#include <hip/hip_bf16.h>

// Fused MHA block. B=4, S=2048, D=768, H=16, DH=48, causal, LayerNorm(eps=1e-3).
// FP32 harness buffers; bf16 MFMA internally (threshold is bf16-lenient, 2% rel).
//
// Pipeline:
//   1. prep     : Wt[n][k] = bf16(W[k][n])  +  Xb = bf16(x) for q,k,v.
//   2. qkv_proj : phase-interleaved MFMA GEMM with counted vmcnt (T3+T4+T5).
//   3. attn     : flash attn on 32x32 MFMA (R6 rewrite):
//                 - QK^T = mfma_32x32x16 x3 (dh=48 exact, no pad waste)
//                 - P-row lane-local (D col=lane&31=q); PV A-frag remap is a
//                   single lane^32 half-exchange (4 shfl + 12 sel per 32k)
//                 - lsum FREE via ones-row at V^T d=48 (PV dtile2 col 48)
//                 - K/V LDS stride-64 + 16B-slot XOR swizzle (R5, proven)
//   4. lnorm    : wave-per-row LayerNorm, no LDS/syncthreads, fp32 out.

#define DMODEL 768
#define NHEAD  16
#define DHEAD  48
#define SEQ    2048
#define NBATCH 4
#define NROWS  (NBATCH * SEQ)                 // 8192
// Q prescale: 1/sqrt(48) * log2(e)  -> softmax = single v_exp_f32 (2^x)
#define QSCALE (0.14433756729740643f * 1.4426950408889634f)

typedef __bf16 bf16x8 __attribute__((ext_vector_type(8)));
typedef float  f32x4  __attribute__((ext_vector_type(4)));
typedef float  f32x16 __attribute__((ext_vector_type(16)));
typedef unsigned int u32x4 __attribute__((ext_vector_type(4)));

static __device__ __forceinline__ unsigned int pk2(float lo, float hi) {
    unsigned short a = __builtin_bit_cast(unsigned short, (__bf16)lo);
    unsigned short b = __builtin_bit_cast(unsigned short, (__bf16)hi);
    return ((unsigned int)b << 16) | a;
}

// ---------------- 1. prep: W transpose+cvt, X cvt ----------------
__global__ __launch_bounds__(256) void prep(
    const float* __restrict__ Wq,
    const float* __restrict__ Wk,
    const float* __restrict__ Wv,
    const float* __restrict__ xq,
    const float* __restrict__ xk,
    const float* __restrict__ xv,
    __hip_bfloat16* __restrict__ Wt,
    __hip_bfloat16* __restrict__ Xbq,
    __hip_bfloat16* __restrict__ Xbk,
    __hip_bfloat16* __restrict__ Xbv)
{
    int bid = blockIdx.x;
    if (bid < 1728) {
        __shared__ __hip_bfloat16 tile[32][33];
        int mat = bid / 576;
        int t   = bid - mat * 576;
        int tr  = t / 24, tc = t - (t / 24) * 24;
        const float* W = (mat == 0) ? Wq : (mat == 1) ? Wk : Wv;
        __hip_bfloat16* O = Wt + (size_t)mat * DMODEL * DMODEL;
        int tx = threadIdx.x & 31, ty = threadIdx.x >> 5;
#pragma unroll
        for (int i = 0; i < 32; i += 8)
            tile[ty + i][tx] = __float2bfloat16(W[(size_t)(tr * 32 + ty + i) * DMODEL + tc * 32 + tx]);
        __syncthreads();
#pragma unroll
        for (int i = 0; i < 32; i += 8)
            O[(size_t)(tc * 32 + ty + i) * DMODEL + tr * 32 + tx] = tile[tx][ty + i];
    } else {
        int b2  = bid - 1728;                 // 0..9215
        int mat = b2 / 3072;
        int r   = b2 - mat * 3072;
        const float* X = (mat == 0) ? xq : (mat == 1) ? xk : xv;
        __hip_bfloat16* O = (mat == 0) ? Xbq : (mat == 1) ? Xbk : Xbv;
        size_t off = (size_t)r * 2048 + threadIdx.x * 8;
        float4 f0 = *(const float4*)(X + off);
        float4 f1 = *(const float4*)(X + off + 4);
        unsigned int w0 = pk2(f0.x, f0.y), w1 = pk2(f0.z, f0.w);
        unsigned int w2 = pk2(f1.x, f1.y), w3 = pk2(f1.z, f1.w);
        u32x4 pv; pv[0] = w0; pv[1] = w1; pv[2] = w2; pv[3] = w3;
        *(u32x4*)(O + off) = pv;
    }
}

// ---------------- 2. QKV projection: phase-interleaved, counted vmcnt --------
__global__ __launch_bounds__(512, 4) void qkv_proj(
    const __hip_bfloat16* __restrict__ Xbq,
    const __hip_bfloat16* __restrict__ Xbk,
    const __hip_bfloat16* __restrict__ Xbv,
    const __hip_bfloat16* __restrict__ Wt,
    const float* __restrict__ bq,
    const float* __restrict__ bk,
    const float* __restrict__ bv,
    __hip_bfloat16* __restrict__ Qr,
    __hip_bfloat16* __restrict__ Kr,
    __hip_bfloat16* __restrict__ Vt)
{
    __shared__ __hip_bfloat16 Abuf[3][8192];   // 3 x 16 KiB
    __shared__ __hip_bfloat16 Bbuf[2][4096];   // 2 x  8 KiB   (total 64 KiB)

    int tid  = threadIdx.x;
    int w    = tid >> 6, lane = tid & 63;
    int l16  = lane & 15, quad = lane >> 4;
    int wm   = w >> 1, wn = w & 1;             // 4M x 2N waves

    int xcd = blockIdx.x & 7, s = blockIdx.x >> 3;
    int nt  = s % 6;
    int idx = (s / 6) * 8 + xcd;               // 0..95
    int mat = idx >> 5, mt = idx & 31;
    int m0  = mt * 256, n0 = nt * 128;

    const __hip_bfloat16* X = (mat == 0) ? Xbq : (mat == 1) ? Xbk : Xbv;
    const __hip_bfloat16* W = Wt + (size_t)mat * DMODEL * DMODEL;
    const float* bias       = (mat == 0) ? bq : (mat == 1) ? bk : bv;

    int sr = tid >> 2, sc = (tid & 3) * 8;
    const __hip_bfloat16* ga0 = X + (size_t)(m0 + sr) * DMODEL + sc;
    const __hip_bfloat16* ga1 = X + (size_t)(m0 + 128 + sr) * DMODEL + sc;
    const __hip_bfloat16* gb  = W + (size_t)(n0 + sr) * DMODEL + sc;

#define GLD(gp_, lp_) __builtin_amdgcn_global_load_lds(                        \
        (const __attribute__((address_space(1))) void*)(gp_),                  \
        (__attribute__((address_space(3))) void*)(lp_), 16, 0, 0)

    int aoff = (wm * 64 + l16) * 32 + quad * 8;
    int boff = (wn * 64 + l16) * 32 + quad * 8;

    f32x4 acc[4][4] = {};

    GLD(gb,       &Bbuf[0][tid * 8]);
    GLD(ga0,      &Abuf[0][tid * 8]);
    GLD(ga1,      &Abuf[0][4096 + tid * 8]);
    GLD(ga0 + 32, &Abuf[1][tid * 8]);
    GLD(ga1 + 32, &Abuf[1][4096 + tid * 8]);
    asm volatile("s_waitcnt vmcnt(2)" ::: "memory");
    asm volatile("s_barrier" ::: "memory");

    int abuf = 0, bbuf = 0, abS = 2;
    const __hip_bfloat16* gbS  = gb  + 32;
    const __hip_bfloat16* ga0S = ga0 + 64;
    const __hip_bfloat16* ga1S = ga1 + 64;

    for (int kt = 0; kt < 24; ++kt) {
        const __hip_bfloat16* LA = Abuf[abuf];
        const __hip_bfloat16* LB = Bbuf[bbuf];

        bf16x8 a[4], bA[2];
#pragma unroll
        for (int m_ = 0; m_ < 4; ++m_)
            a[m_] = *(const bf16x8*)&LA[aoff + m_ * 512];
        bA[0] = *(const bf16x8*)&LB[boff];
        bA[1] = *(const bf16x8*)&LB[boff + 512];

        if (kt < 23) { GLD(gbS, &Bbuf[bbuf ^ 1][tid * 8]); gbS += 32; }
        if (kt < 22) {
            GLD(ga0S, &Abuf[abS][tid * 8]);
            GLD(ga1S, &Abuf[abS][4096 + tid * 8]);
            ga0S += 32; ga1S += 32;
        }

        asm volatile("s_barrier" ::: "memory");
        __builtin_amdgcn_s_setprio(1);
#pragma unroll
        for (int m_ = 0; m_ < 4; ++m_) {
            acc[m_][0] = __builtin_amdgcn_mfma_f32_16x16x32_bf16(a[m_], bA[0], acc[m_][0], 0, 0, 0);
            acc[m_][1] = __builtin_amdgcn_mfma_f32_16x16x32_bf16(a[m_], bA[1], acc[m_][1], 0, 0, 0);
        }
        __builtin_amdgcn_s_setprio(0);
        asm volatile("s_barrier" ::: "memory");

        bf16x8 bB[2];
        bB[0] = *(const bf16x8*)&LB[boff + 1024];
        bB[1] = *(const bf16x8*)&LB[boff + 1536];

        if (kt < 22) asm volatile("s_waitcnt vmcnt(2)" ::: "memory");
        else         asm volatile("s_waitcnt vmcnt(0)" ::: "memory");
        asm volatile("s_barrier" ::: "memory");
        __builtin_amdgcn_s_setprio(1);
#pragma unroll
        for (int m_ = 0; m_ < 4; ++m_) {
            acc[m_][2] = __builtin_amdgcn_mfma_f32_16x16x32_bf16(a[m_], bB[0], acc[m_][2], 0, 0, 0);
            acc[m_][3] = __builtin_amdgcn_mfma_f32_16x16x32_bf16(a[m_], bB[1], acc[m_][3], 0, 0, 0);
        }
        __builtin_amdgcn_s_setprio(0);
        asm volatile("s_barrier" ::: "memory");

        abuf = (abuf == 2) ? 0 : abuf + 1;
        abS  = (abS  == 2) ? 0 : abS  + 1;
        bbuf ^= 1;
    }
#undef GLD

    // epilogue
#pragma unroll
    for (int j = 0; j < 4; ++j) {
        int col = n0 + wn * 64 + j * 16 + l16;
        float bc = bias[col];
        if (mat == 0) {
#pragma unroll
            for (int i = 0; i < 4; ++i) {
                int row0 = m0 + wm * 64 + i * 16 + quad * 4;
#pragma unroll
                for (int r = 0; r < 4; ++r)
                    Qr[(size_t)(row0 + r) * DMODEL + col] =
                        __float2bfloat16((acc[i][j][r] + bc) * QSCALE);
            }
        } else if (mat == 1) {
#pragma unroll
            for (int i = 0; i < 4; ++i) {
                int row0 = m0 + wm * 64 + i * 16 + quad * 4;
#pragma unroll
                for (int r = 0; r < 4; ++r)
                    Kr[(size_t)(row0 + r) * DMODEL + col] =
                        __float2bfloat16(acc[i][j][r] + bc);
            }
        } else {
            int h = col / 48, dh = col - h * 48;
#pragma unroll
            for (int i = 0; i < 4; ++i) {
                int row0 = m0 + wm * 64 + i * 16 + quad * 4;
                int bb = row0 >> 11, s0 = row0 & 2047;
                unsigned int lo = pk2(acc[i][j][0] + bc, acc[i][j][1] + bc);
                unsigned int hi = pk2(acc[i][j][2] + bc, acc[i][j][3] + bc);
                uint2 pw; pw.x = lo; pw.y = hi;
                *(uint2*)(Vt + ((size_t)(bb * NHEAD + h) * DHEAD + dh) * SEQ + s0) = pw;
            }
        }
    }
}

// ---------------- 3. MFMA causal flash attention, 32x32 shape ------------
// Per wave: 32 q rows. QK^T: S[k][q] via mfma_32x32x16 (A=K, B=Q^T, 3 dh-slices).
// S frag: q=lane&31, k=(reg&3)+8*(reg>>2)+4*half. PV A-frag k=8*half+j: one
// lane^32 exchange (4 shfl_xor + selects). V^T row 48 = ones -> PV dtile2
// col 48 accumulates the row sum (free lsum).
__global__ __launch_bounds__(256, 3) void attn(
    const __hip_bfloat16* __restrict__ Qr,
    const __hip_bfloat16* __restrict__ Kr,
    const __hip_bfloat16* __restrict__ Vt,
    __hip_bfloat16* __restrict__ Ao)
{
    __shared__ __hip_bfloat16 Ks[2][64][64];   // 16 KiB (slots 0..5 = dh 0..47)
    __shared__ __hip_bfloat16 Vs[2][64][64];   // 16 KiB (rows 0..47 = V^T, 48 = ones, 49..63 = 0)

    int tid  = threadIdx.x;
    int w    = tid >> 6, lane = tid & 63;
    int l31  = lane & 31;
    int half = lane >> 5;
    bool hb  = half != 0;
    int bh   = blockIdx.x & 63;
    int qt   = 15 - (blockIdx.x >> 6);         // heavy q-tiles dispatch first
    int q0   = qt * 128;
    int b    = bh >> 4, h = bh & 15;           // h = head
    size_t rowbase = (size_t)b * SEQ;

    const __hip_bfloat16* Qp = Qr + rowbase * DMODEL + h * DHEAD;
    const __hip_bfloat16* Kp = Kr + rowbase * DMODEL + h * DHEAD;
    const __hip_bfloat16* Vp = Vt + (size_t)bh * DHEAD * SEQ;

    // init Vs pad rows 48..63 (row 48 = ones for the lsum column, rest 0),
    // both buffers: 2 x 16 rows x 8 slots = 256 chunks of 16B, one per thread
    {
        int zbuf = tid >> 7, zi = tid & 127;
        int zr = 48 + (zi >> 3), zsl = zi & 7;
        unsigned int v = (zr == 48) ? 0x3F803F80u : 0u;
        u32x4 pv; pv[0] = v; pv[1] = v; pv[2] = v; pv[3] = v;
        *(u32x4*)&Vs[zbuf][zr][(zsl ^ (zr & 7)) * 8] = pv;
    }

    // Q B-frags: B[col=q=l31][dh = t*16 + half*8 + j], 3 dh-slices
    int q0w = q0 + w * 32;
    bf16x8 bQ0, bQ1, bQ2;
    {
        const __hip_bfloat16* qp = Qp + (size_t)(q0w + l31) * DMODEL + half * 8;
        bQ0 = *(const bf16x8*)(qp);
        bQ1 = *(const bf16x8*)(qp + 16);
        bQ2 = *(const bf16x8*)(qp + 32);
    }

    // staging chunk maps (R5, proven): K = 384 chunks (64r x 6 slots),
    // V = 384 chunks (48r x 8 slots); thread t: chunk t, and t+256 if t<128.
    int kr1 = tid / 6,          ksl1 = tid - kr1 * 6;
    int kr2 = (tid + 256) / 6,  ksl2 = (tid + 256) - kr2 * 6;
    int vd1 = tid >> 3,         vsl1 = tid & 7;
    int vd2 = (tid + 256) >> 3, vsl2 = tid & 7;
    int kso1 = (ksl1 ^ (kr1 & 7)) * 8;
    int kso2 = (ksl2 ^ (kr2 & 7)) * 8;
    int vso1 = (vsl1 ^ (vd1 & 7)) * 8;
    int vso2 = (vsl2 ^ (vd2 & 7)) * 8;

    uint4 kv1, kv2, vv1, vv2;

#define ATTN_LOAD(kt_) {                                                        \
        int k0_ = (kt_) * 64;                                                   \
        kv1 = *(const uint4*)(Kp + (size_t)(k0_ + kr1) * DMODEL + ksl1 * 8);    \
        vv1 = *(const uint4*)(Vp + (size_t)vd1 * SEQ + k0_ + vsl1 * 8);         \
        if (tid < 128) {                                                        \
            kv2 = *(const uint4*)(Kp + (size_t)(k0_ + kr2) * DMODEL + ksl2 * 8);\
            vv2 = *(const uint4*)(Vp + (size_t)vd2 * SEQ + k0_ + vsl2 * 8);     \
        } }

#define ATTN_STORE(buf_) {                                                      \
        *(uint4*)&Ks[buf_][kr1][kso1] = kv1;                                    \
        *(uint4*)&Vs[buf_][vd1][vso1] = vv1;                                    \
        if (tid < 128) {                                                        \
            *(uint4*)&Ks[buf_][kr2][kso2] = kv2;                                \
            *(uint4*)&Vs[buf_][vd2][vso2] = vv2;                                \
        } }

#define MFMA32(A_, B_, C_) __builtin_amdgcn_mfma_f32_32x32x16_bf16(A_, B_, C_, 0, 0, 0)

    f32x16 O1 = {}, O2 = {};
    const f32x16 z16 = {};

    int ktmax = 2 * qt + 1;
    ATTN_LOAD(0);
    ATTN_STORE(0);
    if (ktmax >= 1) ATTN_LOAD(1);
    __syncthreads();

    for (int kt = 0; kt <= ktmax; ++kt) {
        int buf = kt & 1;
        int k0  = kt * 64;
        if (kt + 1 <= ktmax) ATTN_STORE(buf ^ 1);
        if (kt + 2 <= ktmax) ATTN_LOAD(kt + 2);

#pragma unroll
        for (int kc = 0; kc < 2; ++kc) {
            int kbase = k0 + kc * 32;
            if (kbase <= q0w + 31) {           // wave-uniform active guard
                // ---- QK^T: A = K rows (kbase..+31), 3 dh-slices ----
                int krow = kc * 32 + l31;
                int ksw  = krow & 7;
                bf16x8 aK0 = *(const bf16x8*)&Ks[buf][krow][((0 + half) ^ ksw) * 8];
                bf16x8 aK1 = *(const bf16x8*)&Ks[buf][krow][((2 + half) ^ ksw) * 8];
                bf16x8 aK2 = *(const bf16x8*)&Ks[buf][krow][((4 + half) ^ ksw) * 8];

                __builtin_amdgcn_s_setprio(1);
                f32x16 s_;
                s_ = MFMA32(aK0, bQ0, z16);
                s_ = MFMA32(aK1, bQ1, s_);
                s_ = MFMA32(aK2, bQ2, s_);
                __builtin_amdgcn_s_setprio(0);

                // ---- causal mask (boundary tiles only) ----
                if (kbase + 31 > q0w) {
                    int qg = q0w + l31;
                    int kb = kbase + (hb ? 4 : 0);
#pragma unroll
                    for (int r = 0; r < 16; ++r) {
                        int kl = (r & 3) + 8 * (r >> 2);
                        if (kb + kl > qg) s_[r] = -1e30f;
                    }
                }

                // ---- exp2 + pack: w(2g)=pk2(e[4g],e[4g+1]) ----
                unsigned int w0, w1, w2, w3, w4, w5, w6, w7;
                {
                    float e0 = exp2f(s_[0]),  e1 = exp2f(s_[1]);
                    float e2 = exp2f(s_[2]),  e3 = exp2f(s_[3]);
                    float e4 = exp2f(s_[4]),  e5 = exp2f(s_[5]);
                    float e6 = exp2f(s_[6]),  e7 = exp2f(s_[7]);
                    float e8 = exp2f(s_[8]),  e9 = exp2f(s_[9]);
                    float ea = exp2f(s_[10]), eb = exp2f(s_[11]);
                    float ec = exp2f(s_[12]), ed = exp2f(s_[13]);
                    float ee = exp2f(s_[14]), ef = exp2f(s_[15]);
                    w0 = pk2(e0, e1); w1 = pk2(e2, e3);
                    w2 = pk2(e4, e5); w3 = pk2(e6, e7);
                    w4 = pk2(e8, e9); w5 = pk2(ea, eb);
                    w6 = pk2(ec, ed); w7 = pk2(ee, ef);
                }

                // ---- half-exchange: build PV A-frags (k contiguous) ----
                unsigned int sx0 = __shfl_xor(hb ? w0 : w2, 32, 64);
                unsigned int sx1 = __shfl_xor(hb ? w1 : w3, 32, 64);
                unsigned int sx2 = __shfl_xor(hb ? w4 : w6, 32, 64);
                unsigned int sx3 = __shfl_xor(hb ? w5 : w7, 32, 64);
                u32x4 F0w, F1w;
                F0w[0] = hb ? sx0 : w0;  F0w[1] = hb ? sx1 : w1;
                F0w[2] = hb ? w2  : sx0; F0w[3] = hb ? w3  : sx1;
                F1w[0] = hb ? sx2 : w4;  F1w[1] = hb ? sx3 : w5;
                F1w[2] = hb ? w6  : sx2; F1w[3] = hb ? w7  : sx3;
                bf16x8 F0 = __builtin_bit_cast(bf16x8, F0w);
                bf16x8 F1 = __builtin_bit_cast(bf16x8, F1w);

                // ---- PV: B[col=d][k], d-tiles {0..31}, {32..63 (48=ones)} ----
                int vr0 = l31, vr1 = 32 + l31;
                int vw0 = vr0 & 7, vw1 = vr1 & 7;
                bf16x8 bV00 = *(const bf16x8*)&Vs[buf][vr0][((kc * 4 + 0 + half) ^ vw0) * 8];
                bf16x8 bV01 = *(const bf16x8*)&Vs[buf][vr1][((kc * 4 + 0 + half) ^ vw1) * 8];
                bf16x8 bV10 = *(const bf16x8*)&Vs[buf][vr0][((kc * 4 + 2 + half) ^ vw0) * 8];
                bf16x8 bV11 = *(const bf16x8*)&Vs[buf][vr1][((kc * 4 + 2 + half) ^ vw1) * 8];

                __builtin_amdgcn_s_setprio(1);
                O1 = MFMA32(F0, bV00, O1);
                O2 = MFMA32(F0, bV01, O2);
                O1 = MFMA32(F1, bV10, O1);
                O2 = MFMA32(F1, bV11, O2);
                __builtin_amdgcn_s_setprio(0);
            }
        }

        asm volatile("s_waitcnt lgkmcnt(0)" ::: "memory");
        __builtin_amdgcn_s_barrier();
        asm volatile("" ::: "memory");
    }

    // epilogue: lsum lives in O2 col 48 (lane l31==16 of own half)
    int lsrc = (lane & 32) + 16;
#pragma unroll
    for (int r = 0; r < 16; ++r) {
        float lden = __shfl(O2[r], lsrc, 64);
        float linv = 1.f / lden;
        int q = q0w + (r & 3) + 8 * (r >> 2) + (hb ? 4 : 0);
        size_t g = (rowbase + q) * DMODEL + h * DHEAD;
        Ao[g + l31] = __float2bfloat16(O1[r] * linv);
        if (l31 < 16)
            Ao[g + 32 + l31] = __float2bfloat16(O2[r] * linv);
    }
#undef ATTN_LOAD
#undef ATTN_STORE
#undef MFMA32
}

// ---------------- 4. LayerNorm (eps = 1e-3), wave-per-row, fp32 out ----------------
__global__ __launch_bounds__(256) void lnorm(
    const __hip_bfloat16* __restrict__ Ao,
    const float* __restrict__ gamma,
    const float* __restrict__ beta,
    float* __restrict__ out)
{
    int tid = threadIdx.x;
    int wv  = tid >> 6, ln = tid & 63;
    int row = blockIdx.x * 4 + wv;
    size_t base = (size_t)row * DMODEL + ln * 4;

    ushort4 u0 = *(const ushort4*)(Ao + base);
    ushort4 u1 = *(const ushort4*)(Ao + base + 256);
    ushort4 u2 = *(const ushort4*)(Ao + base + 512);
    float x0, x1, x2, x3, x4, x5, x6, x7, x8, x9, xa, xb;
    { unsigned int v = (unsigned int)u0.x << 16; __builtin_memcpy(&x0, &v, 4); }
    { unsigned int v = (unsigned int)u0.y << 16; __builtin_memcpy(&x1, &v, 4); }
    { unsigned int v = (unsigned int)u0.z << 16; __builtin_memcpy(&x2, &v, 4); }
    { unsigned int v = (unsigned int)u0.w << 16; __builtin_memcpy(&x3, &v, 4); }
    { unsigned int v = (unsigned int)u1.x << 16; __builtin_memcpy(&x4, &v, 4); }
    { unsigned int v = (unsigned int)u1.y << 16; __builtin_memcpy(&x5, &v, 4); }
    { unsigned int v = (unsigned int)u1.z << 16; __builtin_memcpy(&x6, &v, 4); }
    { unsigned int v = (unsigned int)u1.w << 16; __builtin_memcpy(&x7, &v, 4); }
    { unsigned int v = (unsigned int)u2.x << 16; __builtin_memcpy(&x8, &v, 4); }
    { unsigned int v = (unsigned int)u2.y << 16; __builtin_memcpy(&x9, &v, 4); }
    { unsigned int v = (unsigned int)u2.z << 16; __builtin_memcpy(&xa, &v, 4); }
    { unsigned int v = (unsigned int)u2.w << 16; __builtin_memcpy(&xb, &v, 4); }

    float s = ((x0 + x1) + (x2 + x3)) + ((x4 + x5) + (x6 + x7)) + ((x8 + x9) + (xa + xb));
    float q = ((x0*x0 + x1*x1) + (x2*x2 + x3*x3)) + ((x4*x4 + x5*x5) + (x6*x6 + x7*x7))
            + ((x8*x8 + x9*x9) + (xa*xa + xb*xb));
#pragma unroll
    for (int m = 32; m >= 1; m >>= 1) {
        s += __shfl_xor(s, m, 64);
        q += __shfl_xor(q, m, 64);
    }
    float mu  = s * (1.f / 768.f);
    float var = q * (1.f / 768.f) - mu * mu;
    float rstd = rsqrtf(var + 1e-3f);

    float4 g0 = *(const float4*)(gamma + ln * 4);
    float4 g1 = *(const float4*)(gamma + ln * 4 + 256);
    float4 g2 = *(const float4*)(gamma + ln * 4 + 512);
    float4 e0 = *(const float4*)(beta + ln * 4);
    float4 e1 = *(const float4*)(beta + ln * 4 + 256);
    float4 e2 = *(const float4*)(beta + ln * 4 + 512);
    float4 o0, o1, o2;
    o0.x = (x0 - mu) * rstd * g0.x + e0.x;
    o0.y = (x1 - mu) * rstd * g0.y + e0.y;
    o0.z = (x2 - mu) * rstd * g0.z + e0.z;
    o0.w = (x3 - mu) * rstd * g0.w + e0.w;
    o1.x = (x4 - mu) * rstd * g1.x + e1.x;
    o1.y = (x5 - mu) * rstd * g1.y + e1.y;
    o1.z = (x6 - mu) * rstd * g1.z + e1.z;
    o1.w = (x7 - mu) * rstd * g1.w + e1.w;
    o2.x = (x8 - mu) * rstd * g2.x + e2.x;
    o2.y = (x9 - mu) * rstd * g2.y + e2.y;
    o2.z = (xa - mu) * rstd * g2.z + e2.z;
    o2.w = (xb - mu) * rstd * g2.w + e2.w;
    *(float4*)(out + base)       = o0;
    *(float4*)(out + base + 256) = o1;
    *(float4*)(out + base + 512) = o2;
}

extern "C" void kernel_launch(void* const* d_in, const int* in_sizes, int n_in,
                              void* d_out, int out_size, void* d_ws, size_t ws_size,
                              hipStream_t stream) {
    const float* q     = (const float*)d_in[0];
    const float* k     = (const float*)d_in[1];
    const float* v     = (const float*)d_in[2];
    const float* Wq    = (const float*)d_in[3];
    const float* bq    = (const float*)d_in[4];
    const float* Wk    = (const float*)d_in[5];
    const float* bk    = (const float*)d_in[6];
    const float* Wv    = (const float*)d_in[7];
    const float* bv    = (const float*)d_in[8];
    const float* gamma = (const float*)d_in[9];
    const float* beta  = (const float*)d_in[10];

    char* basep = (char*)d_ws;
    __hip_bfloat16* Wt = (__hip_bfloat16*)basep;
    __hip_bfloat16* Qr = (__hip_bfloat16*)(basep + 3538944);
    __hip_bfloat16* Kr = Qr + (size_t)NROWS * DMODEL;
    __hip_bfloat16* Vt = Kr + (size_t)NROWS * DMODEL;
    __hip_bfloat16* Ao = Vt + (size_t)NROWS * DMODEL;
    float* out = (float*)d_out;

    __hip_bfloat16* Xbq = (__hip_bfloat16*)d_out;
    __hip_bfloat16* Xbk = Xbq + (size_t)NROWS * DMODEL;
    __hip_bfloat16* Xbv = Ao;

    hipLaunchKernelGGL(prep, dim3(10944), dim3(256), 0, stream,
                       Wq, Wk, Wv, q, k, v, Wt, Xbq, Xbk, Xbv);
    hipLaunchKernelGGL(qkv_proj, dim3(576), dim3(512), 0, stream,
                       Xbq, Xbk, Xbv, Wt, bq, bk, bv, Qr, Kr, Vt);
    hipLaunchKernelGGL(attn, dim3(1024), dim3(256), 0, stream, Qr, Kr, Vt, Ao);
    hipLaunchKernelGGL(lnorm, dim3(2048), dim3(256), 0, stream, Ao, gamma, beta, out);
}

// Round 7
// 240.144 us; speedup vs baseline: 1.6385x; 1.0850x over previous
//
#include <hip/hip_runtime.h>
#include <hip/hip_bf16.h>

// Fused MHA block. B=4, S=2048, D=768, H=16, DH=48, causal, LayerNorm(eps=1e-3).
// FP32 harness buffers; bf16 MFMA internally (threshold is bf16-lenient, 2% rel).
//
// Pipeline:
//   1. prep     : Wt[n][k] = bf16(W[k][n])  +  Xb = bf16(x) for q,k,v.
//   2. qkv_proj : phase-interleaved MFMA GEMM with counted vmcnt (T3+T4+T5).
//   3. attn     : flash attn on 32x32 MFMA. R7 (VALU-issue diet):
//                 - raw v_exp_f32 via __builtin_amdgcn_exp2f (no guard seq)
//                 - v_permlane32_swap_b32 for the half-exchange (replaces
//                   4 ds_bpermute + 8 cndmask per kc with 4 VALU ops)
//                 - incrementing staging pointers (no per-tile 64b addr math)
//   4. lnorm    : wave-per-row LayerNorm, no LDS/syncthreads, fp32 out.

#define DMODEL 768
#define NHEAD  16
#define DHEAD  48
#define SEQ    2048
#define NBATCH 4
#define NROWS  (NBATCH * SEQ)                 // 8192
// Q prescale: 1/sqrt(48) * log2(e)  -> softmax = single v_exp_f32 (2^x)
#define QSCALE (0.14433756729740643f * 1.4426950408889634f)

typedef __bf16 bf16x8 __attribute__((ext_vector_type(8)));
typedef float  f32x4  __attribute__((ext_vector_type(4)));
typedef float  f32x16 __attribute__((ext_vector_type(16)));
typedef unsigned int u32x4 __attribute__((ext_vector_type(4)));

#if __has_builtin(__builtin_amdgcn_exp2f)
#define EXP2(x) __builtin_amdgcn_exp2f(x)
#else
#define EXP2(x) exp2f(x)
#endif

static __device__ __forceinline__ unsigned int pk2(float lo, float hi) {
    unsigned short a = __builtin_bit_cast(unsigned short, (__bf16)lo);
    unsigned short b = __builtin_bit_cast(unsigned short, (__bf16)hi);
    return ((unsigned int)b << 16) | a;
}

// ---------------- 1. prep: W transpose+cvt, X cvt ----------------
__global__ __launch_bounds__(256) void prep(
    const float* __restrict__ Wq,
    const float* __restrict__ Wk,
    const float* __restrict__ Wv,
    const float* __restrict__ xq,
    const float* __restrict__ xk,
    const float* __restrict__ xv,
    __hip_bfloat16* __restrict__ Wt,
    __hip_bfloat16* __restrict__ Xbq,
    __hip_bfloat16* __restrict__ Xbk,
    __hip_bfloat16* __restrict__ Xbv)
{
    int bid = blockIdx.x;
    if (bid < 1728) {
        __shared__ __hip_bfloat16 tile[32][33];
        int mat = bid / 576;
        int t   = bid - mat * 576;
        int tr  = t / 24, tc = t - (t / 24) * 24;
        const float* W = (mat == 0) ? Wq : (mat == 1) ? Wk : Wv;
        __hip_bfloat16* O = Wt + (size_t)mat * DMODEL * DMODEL;
        int tx = threadIdx.x & 31, ty = threadIdx.x >> 5;
#pragma unroll
        for (int i = 0; i < 32; i += 8)
            tile[ty + i][tx] = __float2bfloat16(W[(size_t)(tr * 32 + ty + i) * DMODEL + tc * 32 + tx]);
        __syncthreads();
#pragma unroll
        for (int i = 0; i < 32; i += 8)
            O[(size_t)(tc * 32 + ty + i) * DMODEL + tr * 32 + tx] = tile[tx][ty + i];
    } else {
        int b2  = bid - 1728;                 // 0..9215
        int mat = b2 / 3072;
        int r   = b2 - mat * 3072;
        const float* X = (mat == 0) ? xq : (mat == 1) ? xk : xv;
        __hip_bfloat16* O = (mat == 0) ? Xbq : (mat == 1) ? Xbk : Xbv;
        size_t off = (size_t)r * 2048 + threadIdx.x * 8;
        float4 f0 = *(const float4*)(X + off);
        float4 f1 = *(const float4*)(X + off + 4);
        unsigned int w0 = pk2(f0.x, f0.y), w1 = pk2(f0.z, f0.w);
        unsigned int w2 = pk2(f1.x, f1.y), w3 = pk2(f1.z, f1.w);
        u32x4 pv; pv[0] = w0; pv[1] = w1; pv[2] = w2; pv[3] = w3;
        *(u32x4*)(O + off) = pv;
    }
}

// ---------------- 2. QKV projection: phase-interleaved, counted vmcnt --------
__global__ __launch_bounds__(512, 4) void qkv_proj(
    const __hip_bfloat16* __restrict__ Xbq,
    const __hip_bfloat16* __restrict__ Xbk,
    const __hip_bfloat16* __restrict__ Xbv,
    const __hip_bfloat16* __restrict__ Wt,
    const float* __restrict__ bq,
    const float* __restrict__ bk,
    const float* __restrict__ bv,
    __hip_bfloat16* __restrict__ Qr,
    __hip_bfloat16* __restrict__ Kr,
    __hip_bfloat16* __restrict__ Vt)
{
    __shared__ __hip_bfloat16 Abuf[3][8192];   // 3 x 16 KiB
    __shared__ __hip_bfloat16 Bbuf[2][4096];   // 2 x  8 KiB   (total 64 KiB)

    int tid  = threadIdx.x;
    int w    = tid >> 6, lane = tid & 63;
    int l16  = lane & 15, quad = lane >> 4;
    int wm   = w >> 1, wn = w & 1;             // 4M x 2N waves

    int xcd = blockIdx.x & 7, s = blockIdx.x >> 3;
    int nt  = s % 6;
    int idx = (s / 6) * 8 + xcd;               // 0..95
    int mat = idx >> 5, mt = idx & 31;
    int m0  = mt * 256, n0 = nt * 128;

    const __hip_bfloat16* X = (mat == 0) ? Xbq : (mat == 1) ? Xbk : Xbv;
    const __hip_bfloat16* W = Wt + (size_t)mat * DMODEL * DMODEL;
    const float* bias       = (mat == 0) ? bq : (mat == 1) ? bk : bv;

    int sr = tid >> 2, sc = (tid & 3) * 8;
    const __hip_bfloat16* ga0 = X + (size_t)(m0 + sr) * DMODEL + sc;
    const __hip_bfloat16* ga1 = X + (size_t)(m0 + 128 + sr) * DMODEL + sc;
    const __hip_bfloat16* gb  = W + (size_t)(n0 + sr) * DMODEL + sc;

#define GLD(gp_, lp_) __builtin_amdgcn_global_load_lds(                        \
        (const __attribute__((address_space(1))) void*)(gp_),                  \
        (__attribute__((address_space(3))) void*)(lp_), 16, 0, 0)

    int aoff = (wm * 64 + l16) * 32 + quad * 8;
    int boff = (wn * 64 + l16) * 32 + quad * 8;

    f32x4 acc[4][4] = {};

    GLD(gb,       &Bbuf[0][tid * 8]);
    GLD(ga0,      &Abuf[0][tid * 8]);
    GLD(ga1,      &Abuf[0][4096 + tid * 8]);
    GLD(ga0 + 32, &Abuf[1][tid * 8]);
    GLD(ga1 + 32, &Abuf[1][4096 + tid * 8]);
    asm volatile("s_waitcnt vmcnt(2)" ::: "memory");
    asm volatile("s_barrier" ::: "memory");

    int abuf = 0, bbuf = 0, abS = 2;
    const __hip_bfloat16* gbS  = gb  + 32;
    const __hip_bfloat16* ga0S = ga0 + 64;
    const __hip_bfloat16* ga1S = ga1 + 64;

    for (int kt = 0; kt < 24; ++kt) {
        const __hip_bfloat16* LA = Abuf[abuf];
        const __hip_bfloat16* LB = Bbuf[bbuf];

        bf16x8 a[4], bA[2];
#pragma unroll
        for (int m_ = 0; m_ < 4; ++m_)
            a[m_] = *(const bf16x8*)&LA[aoff + m_ * 512];
        bA[0] = *(const bf16x8*)&LB[boff];
        bA[1] = *(const bf16x8*)&LB[boff + 512];

        if (kt < 23) { GLD(gbS, &Bbuf[bbuf ^ 1][tid * 8]); gbS += 32; }
        if (kt < 22) {
            GLD(ga0S, &Abuf[abS][tid * 8]);
            GLD(ga1S, &Abuf[abS][4096 + tid * 8]);
            ga0S += 32; ga1S += 32;
        }

        asm volatile("s_barrier" ::: "memory");
        __builtin_amdgcn_s_setprio(1);
#pragma unroll
        for (int m_ = 0; m_ < 4; ++m_) {
            acc[m_][0] = __builtin_amdgcn_mfma_f32_16x16x32_bf16(a[m_], bA[0], acc[m_][0], 0, 0, 0);
            acc[m_][1] = __builtin_amdgcn_mfma_f32_16x16x32_bf16(a[m_], bA[1], acc[m_][1], 0, 0, 0);
        }
        __builtin_amdgcn_s_setprio(0);
        asm volatile("s_barrier" ::: "memory");

        bf16x8 bB[2];
        bB[0] = *(const bf16x8*)&LB[boff + 1024];
        bB[1] = *(const bf16x8*)&LB[boff + 1536];

        if (kt < 22) asm volatile("s_waitcnt vmcnt(2)" ::: "memory");
        else         asm volatile("s_waitcnt vmcnt(0)" ::: "memory");
        asm volatile("s_barrier" ::: "memory");
        __builtin_amdgcn_s_setprio(1);
#pragma unroll
        for (int m_ = 0; m_ < 4; ++m_) {
            acc[m_][2] = __builtin_amdgcn_mfma_f32_16x16x32_bf16(a[m_], bB[0], acc[m_][2], 0, 0, 0);
            acc[m_][3] = __builtin_amdgcn_mfma_f32_16x16x32_bf16(a[m_], bB[1], acc[m_][3], 0, 0, 0);
        }
        __builtin_amdgcn_s_setprio(0);
        asm volatile("s_barrier" ::: "memory");

        abuf = (abuf == 2) ? 0 : abuf + 1;
        abS  = (abS  == 2) ? 0 : abS  + 1;
        bbuf ^= 1;
    }
#undef GLD

    // epilogue
#pragma unroll
    for (int j = 0; j < 4; ++j) {
        int col = n0 + wn * 64 + j * 16 + l16;
        float bc = bias[col];
        if (mat == 0) {
#pragma unroll
            for (int i = 0; i < 4; ++i) {
                int row0 = m0 + wm * 64 + i * 16 + quad * 4;
#pragma unroll
                for (int r = 0; r < 4; ++r)
                    Qr[(size_t)(row0 + r) * DMODEL + col] =
                        __float2bfloat16((acc[i][j][r] + bc) * QSCALE);
            }
        } else if (mat == 1) {
#pragma unroll
            for (int i = 0; i < 4; ++i) {
                int row0 = m0 + wm * 64 + i * 16 + quad * 4;
#pragma unroll
                for (int r = 0; r < 4; ++r)
                    Kr[(size_t)(row0 + r) * DMODEL + col] =
                        __float2bfloat16(acc[i][j][r] + bc);
            }
        } else {
            int h = col / 48, dh = col - h * 48;
#pragma unroll
            for (int i = 0; i < 4; ++i) {
                int row0 = m0 + wm * 64 + i * 16 + quad * 4;
                int bb = row0 >> 11, s0 = row0 & 2047;
                unsigned int lo = pk2(acc[i][j][0] + bc, acc[i][j][1] + bc);
                unsigned int hi = pk2(acc[i][j][2] + bc, acc[i][j][3] + bc);
                uint2 pw; pw.x = lo; pw.y = hi;
                *(uint2*)(Vt + ((size_t)(bb * NHEAD + h) * DHEAD + dh) * SEQ + s0) = pw;
            }
        }
    }
}

// ---------------- 3. MFMA causal flash attention, 32x32 shape ------------
// Per wave: 32 q rows. QK^T: S[k][q] via mfma_32x32x16 (A=K, B=Q^T, 3 dh-slices).
// S frag: q=lane&31, k=(reg&3)+8*(reg>>2)+4*half. PV A-frag k=8*half+j via
// v_permlane32_swap_b32 (new_a=[a.lo|b.lo^], new_b=[a.hi_v|b.hi] — exactly the
// needed half-exchange, both outputs used). V^T row 48 = ones -> PV dtile2
// col 48 accumulates the row sum (free lsum).
__global__ __launch_bounds__(256, 3) void attn(
    const __hip_bfloat16* __restrict__ Qr,
    const __hip_bfloat16* __restrict__ Kr,
    const __hip_bfloat16* __restrict__ Vt,
    __hip_bfloat16* __restrict__ Ao)
{
    __shared__ __hip_bfloat16 Ks[2][64][64];   // 16 KiB (slots 0..5 = dh 0..47)
    __shared__ __hip_bfloat16 Vs[2][64][64];   // 16 KiB (rows 0..47 = V^T, 48 = ones, 49..63 = 0)

    int tid  = threadIdx.x;
    int w    = tid >> 6, lane = tid & 63;
    int l31  = lane & 31;
    int half = lane >> 5;
    bool hb  = half != 0;
    int bh   = blockIdx.x & 63;
    int qt   = 15 - (blockIdx.x >> 6);         // heavy q-tiles dispatch first
    int q0   = qt * 128;
    int b    = bh >> 4, h = bh & 15;           // h = head
    size_t rowbase = (size_t)b * SEQ;

    const __hip_bfloat16* Qp = Qr + rowbase * DMODEL + h * DHEAD;
    const __hip_bfloat16* Kp = Kr + rowbase * DMODEL + h * DHEAD;
    const __hip_bfloat16* Vp = Vt + (size_t)bh * DHEAD * SEQ;

    // init Vs pad rows 48..63 (row 48 = ones for the lsum column, rest 0)
    {
        int zbuf = tid >> 7, zi = tid & 127;
        int zr = 48 + (zi >> 3), zsl = zi & 7;
        unsigned int v = (zr == 48) ? 0x3F803F80u : 0u;
        u32x4 pv; pv[0] = v; pv[1] = v; pv[2] = v; pv[3] = v;
        *(u32x4*)&Vs[zbuf][zr][(zsl ^ (zr & 7)) * 8] = pv;
    }

    // Q B-frags: B[col=q=l31][dh = t*16 + half*8 + j], 3 dh-slices
    int q0w = q0 + w * 32;
    bf16x8 bQ0, bQ1, bQ2;
    {
        const __hip_bfloat16* qp = Qp + (size_t)(q0w + l31) * DMODEL + half * 8;
        bQ0 = *(const bf16x8*)(qp);
        bQ1 = *(const bf16x8*)(qp + 16);
        bQ2 = *(const bf16x8*)(qp + 32);
    }

    // staging chunk maps (proven): K = 384 chunks (64r x 6 slots),
    // V = 384 chunks (48r x 8 slots); thread t: chunk t, and t+256 if t<128.
    int kr1 = tid / 6,          ksl1 = tid - kr1 * 6;
    int kr2 = (tid + 256) / 6,  ksl2 = (tid + 256) - kr2 * 6;
    int vd1 = tid >> 3,         vsl1 = tid & 7;
    int vd2 = (tid + 256) >> 3, vsl2 = tid & 7;
    int kso1 = (ksl1 ^ (kr1 & 7)) * 8;
    int kso2 = (ksl2 ^ (kr2 & 7)) * 8;
    int vso1 = (vsl1 ^ (vd1 & 7)) * 8;
    int vso2 = (vsl2 ^ (vd2 & 7)) * 8;

    // incrementing staging source pointers (advance once per ATTN_LOAD)
    const __hip_bfloat16* pK1 = Kp + (size_t)kr1 * DMODEL + ksl1 * 8;
    const __hip_bfloat16* pK2 = Kp + (size_t)kr2 * DMODEL + ksl2 * 8;
    const __hip_bfloat16* pV1 = Vp + (size_t)vd1 * SEQ + vsl1 * 8;
    const __hip_bfloat16* pV2 = Vp + (size_t)vd2 * SEQ + vsl2 * 8;

    uint4 kv1, kv2, vv1, vv2;

#define ATTN_LOAD() {                                                           \
        kv1 = *(const uint4*)pK1;                                               \
        vv1 = *(const uint4*)pV1;                                               \
        if (tid < 128) {                                                        \
            kv2 = *(const uint4*)pK2;                                           \
            vv2 = *(const uint4*)pV2;                                           \
        }                                                                       \
        pK1 += 64 * DMODEL; pK2 += 64 * DMODEL; pV1 += 64; pV2 += 64; }

#define ATTN_STORE(buf_) {                                                      \
        *(uint4*)&Ks[buf_][kr1][kso1] = kv1;                                    \
        *(uint4*)&Vs[buf_][vd1][vso1] = vv1;                                    \
        if (tid < 128) {                                                        \
            *(uint4*)&Ks[buf_][kr2][kso2] = kv2;                                \
            *(uint4*)&Vs[buf_][vd2][vso2] = vv2;                                \
        } }

#define MFMA32(A_, B_, C_) __builtin_amdgcn_mfma_f32_32x32x16_bf16(A_, B_, C_, 0, 0, 0)

    f32x16 O1 = {}, O2 = {};
    const f32x16 z16 = {};

    int ktmax = 2 * qt + 1;                    // >= 1 always
    ATTN_LOAD();
    ATTN_STORE(0);
    ATTN_LOAD();
    __syncthreads();

    for (int kt = 0; kt <= ktmax; ++kt) {
        int buf = kt & 1;
        int k0  = kt * 64;
        if (kt + 1 <= ktmax) ATTN_STORE(buf ^ 1);
        if (kt + 2 <= ktmax) ATTN_LOAD();

#pragma unroll
        for (int kc = 0; kc < 2; ++kc) {
            int kbase = k0 + kc * 32;
            if (kbase <= q0w + 31) {           // wave-uniform active guard
                // ---- QK^T: A = K rows (kbase..+31), 3 dh-slices ----
                int krow = kc * 32 + l31;
                int ksw  = krow & 7;
                bf16x8 aK0 = *(const bf16x8*)&Ks[buf][krow][((0 + half) ^ ksw) * 8];
                bf16x8 aK1 = *(const bf16x8*)&Ks[buf][krow][((2 + half) ^ ksw) * 8];
                bf16x8 aK2 = *(const bf16x8*)&Ks[buf][krow][((4 + half) ^ ksw) * 8];

                __builtin_amdgcn_s_setprio(1);
                f32x16 s_;
                s_ = MFMA32(aK0, bQ0, z16);
                s_ = MFMA32(aK1, bQ1, s_);
                s_ = MFMA32(aK2, bQ2, s_);
                __builtin_amdgcn_s_setprio(0);

                // ---- causal mask (boundary tiles only) ----
                if (kbase + 31 > q0w) {
                    int qg = q0w + l31;
                    int kb = kbase + (hb ? 4 : 0);
#pragma unroll
                    for (int r = 0; r < 16; ++r) {
                        int kl = (r & 3) + 8 * (r >> 2);
                        if (kb + kl > qg) s_[r] = -1e30f;
                    }
                }

                // ---- exp2 (raw v_exp_f32) + pack ----
                unsigned int p0, p1, p2, p3, p4, p5, p6, p7;
                {
                    float e0 = EXP2(s_[0]),  e1 = EXP2(s_[1]);
                    float e2 = EXP2(s_[2]),  e3 = EXP2(s_[3]);
                    float e4 = EXP2(s_[4]),  e5 = EXP2(s_[5]);
                    float e6 = EXP2(s_[6]),  e7 = EXP2(s_[7]);
                    float e8 = EXP2(s_[8]),  e9 = EXP2(s_[9]);
                    float ea = EXP2(s_[10]), eb = EXP2(s_[11]);
                    float ec = EXP2(s_[12]), ed = EXP2(s_[13]);
                    float ee = EXP2(s_[14]), ef = EXP2(s_[15]);
                    p0 = pk2(e0, e1); p1 = pk2(e2, e3);
                    p2 = pk2(e4, e5); p3 = pk2(e6, e7);
                    p4 = pk2(e8, e9); p5 = pk2(ea, eb);
                    p6 = pk2(ec, ed); p7 = pk2(ee, ef);
                }

                // ---- half-exchange -> PV A-frags ----
                u32x4 F0w, F1w;
#if __has_builtin(__builtin_amdgcn_permlane32_swap)
                {
                    typedef unsigned int u32x2 __attribute__((ext_vector_type(2)));
                    u32x2 r0 = __builtin_amdgcn_permlane32_swap(p0, p2, false, false);
                    u32x2 r1 = __builtin_amdgcn_permlane32_swap(p1, p3, false, false);
                    u32x2 r2 = __builtin_amdgcn_permlane32_swap(p4, p6, false, false);
                    u32x2 r3 = __builtin_amdgcn_permlane32_swap(p5, p7, false, false);
                    F0w[0] = r0[0]; F0w[1] = r1[0]; F0w[2] = r0[1]; F0w[3] = r1[1];
                    F1w[0] = r2[0]; F1w[1] = r3[0]; F1w[2] = r2[1]; F1w[3] = r3[1];
                }
#else
                {
                    unsigned int sx0 = __shfl_xor(hb ? p0 : p2, 32, 64);
                    unsigned int sx1 = __shfl_xor(hb ? p1 : p3, 32, 64);
                    unsigned int sx2 = __shfl_xor(hb ? p4 : p6, 32, 64);
                    unsigned int sx3 = __shfl_xor(hb ? p5 : p7, 32, 64);
                    F0w[0] = hb ? sx0 : p0;  F0w[1] = hb ? sx1 : p1;
                    F0w[2] = hb ? p2  : sx0; F0w[3] = hb ? p3  : sx1;
                    F1w[0] = hb ? sx2 : p4;  F1w[1] = hb ? sx3 : p5;
                    F1w[2] = hb ? p6  : sx2; F1w[3] = hb ? p7  : sx3;
                }
#endif
                bf16x8 F0 = __builtin_bit_cast(bf16x8, F0w);
                bf16x8 F1 = __builtin_bit_cast(bf16x8, F1w);

                // ---- PV: B[col=d][k], d-tiles {0..31}, {32..63 (48=ones)} ----
                int vr0 = l31, vr1 = 32 + l31;
                int vw0 = vr0 & 7, vw1 = vr1 & 7;
                bf16x8 bV00 = *(const bf16x8*)&Vs[buf][vr0][((kc * 4 + 0 + half) ^ vw0) * 8];
                bf16x8 bV01 = *(const bf16x8*)&Vs[buf][vr1][((kc * 4 + 0 + half) ^ vw1) * 8];
                bf16x8 bV10 = *(const bf16x8*)&Vs[buf][vr0][((kc * 4 + 2 + half) ^ vw0) * 8];
                bf16x8 bV11 = *(const bf16x8*)&Vs[buf][vr1][((kc * 4 + 2 + half) ^ vw1) * 8];

                __builtin_amdgcn_s_setprio(1);
                O1 = MFMA32(F0, bV00, O1);
                O2 = MFMA32(F0, bV01, O2);
                O1 = MFMA32(F1, bV10, O1);
                O2 = MFMA32(F1, bV11, O2);
                __builtin_amdgcn_s_setprio(0);
            }
        }

        asm volatile("s_waitcnt lgkmcnt(0)" ::: "memory");
        __builtin_amdgcn_s_barrier();
        asm volatile("" ::: "memory");
    }

    // epilogue: lsum lives in O2 col 48 (lane l31==16 of own half)
    int lsrc = (lane & 32) + 16;
#pragma unroll
    for (int r = 0; r < 16; ++r) {
        float lden = __shfl(O2[r], lsrc, 64);
        float linv = 1.f / lden;
        int q = q0w + (r & 3) + 8 * (r >> 2) + (hb ? 4 : 0);
        size_t g = (rowbase + q) * DMODEL + h * DHEAD;
        Ao[g + l31] = __float2bfloat16(O1[r] * linv);
        if (l31 < 16)
            Ao[g + 32 + l31] = __float2bfloat16(O2[r] * linv);
    }
#undef ATTN_LOAD
#undef ATTN_STORE
#undef MFMA32
}

// ---------------- 4. LayerNorm (eps = 1e-3), wave-per-row, fp32 out ----------------
__global__ __launch_bounds__(256) void lnorm(
    const __hip_bfloat16* __restrict__ Ao,
    const float* __restrict__ gamma,
    const float* __restrict__ beta,
    float* __restrict__ out)
{
    int tid = threadIdx.x;
    int wv  = tid >> 6, ln = tid & 63;
    int row = blockIdx.x * 4 + wv;
    size_t base = (size_t)row * DMODEL + ln * 4;

    ushort4 u0 = *(const ushort4*)(Ao + base);
    ushort4 u1 = *(const ushort4*)(Ao + base + 256);
    ushort4 u2 = *(const ushort4*)(Ao + base + 512);
    float x0, x1, x2, x3, x4, x5, x6, x7, x8, x9, xa, xb;
    { unsigned int v = (unsigned int)u0.x << 16; __builtin_memcpy(&x0, &v, 4); }
    { unsigned int v = (unsigned int)u0.y << 16; __builtin_memcpy(&x1, &v, 4); }
    { unsigned int v = (unsigned int)u0.z << 16; __builtin_memcpy(&x2, &v, 4); }
    { unsigned int v = (unsigned int)u0.w << 16; __builtin_memcpy(&x3, &v, 4); }
    { unsigned int v = (unsigned int)u1.x << 16; __builtin_memcpy(&x4, &v, 4); }
    { unsigned int v = (unsigned int)u1.y << 16; __builtin_memcpy(&x5, &v, 4); }
    { unsigned int v = (unsigned int)u1.z << 16; __builtin_memcpy(&x6, &v, 4); }
    { unsigned int v = (unsigned int)u1.w << 16; __builtin_memcpy(&x7, &v, 4); }
    { unsigned int v = (unsigned int)u2.x << 16; __builtin_memcpy(&x8, &v, 4); }
    { unsigned int v = (unsigned int)u2.y << 16; __builtin_memcpy(&x9, &v, 4); }
    { unsigned int v = (unsigned int)u2.z << 16; __builtin_memcpy(&xa, &v, 4); }
    { unsigned int v = (unsigned int)u2.w << 16; __builtin_memcpy(&xb, &v, 4); }

    float s = ((x0 + x1) + (x2 + x3)) + ((x4 + x5) + (x6 + x7)) + ((x8 + x9) + (xa + xb));
    float q = ((x0*x0 + x1*x1) + (x2*x2 + x3*x3)) + ((x4*x4 + x5*x5) + (x6*x6 + x7*x7))
            + ((x8*x8 + x9*x9) + (xa*xa + xb*xb));
#pragma unroll
    for (int m = 32; m >= 1; m >>= 1) {
        s += __shfl_xor(s, m, 64);
        q += __shfl_xor(q, m, 64);
    }
    float mu  = s * (1.f / 768.f);
    float var = q * (1.f / 768.f) - mu * mu;
    float rstd = rsqrtf(var + 1e-3f);

    float4 g0 = *(const float4*)(gamma + ln * 4);
    float4 g1 = *(const float4*)(gamma + ln * 4 + 256);
    float4 g2 = *(const float4*)(gamma + ln * 4 + 512);
    float4 e0 = *(const float4*)(beta + ln * 4);
    float4 e1 = *(const float4*)(beta + ln * 4 + 256);
    float4 e2 = *(const float4*)(beta + ln * 4 + 512);
    float4 o0, o1, o2;
    o0.x = (x0 - mu) * rstd * g0.x + e0.x;
    o0.y = (x1 - mu) * rstd * g0.y + e0.y;
    o0.z = (x2 - mu) * rstd * g0.z + e0.z;
    o0.w = (x3 - mu) * rstd * g0.w + e0.w;
    o1.x = (x4 - mu) * rstd * g1.x + e1.x;
    o1.y = (x5 - mu) * rstd * g1.y + e1.y;
    o1.z = (x6 - mu) * rstd * g1.z + e1.z;
    o1.w = (x7 - mu) * rstd * g1.w + e1.w;
    o2.x = (x8 - mu) * rstd * g2.x + e2.x;
    o2.y = (x9 - mu) * rstd * g2.y + e2.y;
    o2.z = (xa - mu) * rstd * g2.z + e2.z;
    o2.w = (xb - mu) * rstd * g2.w + e2.w;
    *(float4*)(out + base)       = o0;
    *(float4*)(out + base + 256) = o1;
    *(float4*)(out + base + 512) = o2;
}

extern "C" void kernel_launch(void* const* d_in, const int* in_sizes, int n_in,
                              void* d_out, int out_size, void* d_ws, size_t ws_size,
                              hipStream_t stream) {
    const float* q     = (const float*)d_in[0];
    const float* k     = (const float*)d_in[1];
    const float* v     = (const float*)d_in[2];
    const float* Wq    = (const float*)d_in[3];
    const float* bq    = (const float*)d_in[4];
    const float* Wk    = (const float*)d_in[5];
    const float* bk    = (const float*)d_in[6];
    const float* Wv    = (const float*)d_in[7];
    const float* bv    = (const float*)d_in[8];
    const float* gamma = (const float*)d_in[9];
    const float* beta  = (const float*)d_in[10];

    char* basep = (char*)d_ws;
    __hip_bfloat16* Wt = (__hip_bfloat16*)basep;
    __hip_bfloat16* Qr = (__hip_bfloat16*)(basep + 3538944);
    __hip_bfloat16* Kr = Qr + (size_t)NROWS * DMODEL;
    __hip_bfloat16* Vt = Kr + (size_t)NROWS * DMODEL;
    __hip_bfloat16* Ao = Vt + (size_t)NROWS * DMODEL;
    float* out = (float*)d_out;

    __hip_bfloat16* Xbq = (__hip_bfloat16*)d_out;
    __hip_bfloat16* Xbk = Xbq + (size_t)NROWS * DMODEL;
    __hip_bfloat16* Xbv = Ao;

    hipLaunchKernelGGL(prep, dim3(10944), dim3(256), 0, stream,
                       Wq, Wk, Wv, q, k, v, Wt, Xbq, Xbk, Xbv);
    hipLaunchKernelGGL(qkv_proj, dim3(576), dim3(512), 0, stream,
                       Xbq, Xbk, Xbv, Wt, bq, bk, bv, Qr, Kr, Vt);
    hipLaunchKernelGGL(attn, dim3(1024), dim3(256), 0, stream, Qr, Kr, Vt, Ao);
    hipLaunchKernelGGL(lnorm, dim3(2048), dim3(256), 0, stream, Ao, gamma, beta, out);
}

// Round 8
// 233.405 us; speedup vs baseline: 1.6858x; 1.0289x over previous
//
#include <hip/hip_runtime.h>
#include <hip/hip_bf16.h>

// Fused MHA block. B=4, S=2048, D=768, H=16, DH=48, causal, LayerNorm(eps=1e-3).
// FP32 harness buffers; bf16 MFMA internally (threshold is bf16-lenient, 2% rel).
//
// Pipeline:
//   1. prep     : Wt[n][k] = bf16(W[k][n])  +  Xb = bf16(x) for q,k,v.
//   2. qkv_proj : phase-interleaved MFMA GEMM with counted vmcnt (T3+T4+T5).
//                 R8: both-sides LDS swizzle (rule #21) — gload_lds dest stays
//                 linear, global SOURCE col is pre-swizzled so chunk (row,slot)
//                 holds k-chunk slot^((row>>1)&3); frag reads use slot
//                 quad^((l16>>1)&3). Kills the 8-way bank conflict (3.54M cyc).
//                 Epilogue j-innermost: 4 stores/row back-to-back -> 128B
//                 write-combine (WRITE_SIZE was 2x ideal).
//   3. attn     : flash attn on 32x32 MFMA (R7: raw exp2, permlane32_swap).
//   4. lnorm    : wave-per-row LayerNorm, no LDS/syncthreads, fp32 out.

#define DMODEL 768
#define NHEAD  16
#define DHEAD  48
#define SEQ    2048
#define NBATCH 4
#define NROWS  (NBATCH * SEQ)                 // 8192
// Q prescale: 1/sqrt(48) * log2(e)  -> softmax = single v_exp_f32 (2^x)
#define QSCALE (0.14433756729740643f * 1.4426950408889634f)

typedef __bf16 bf16x8 __attribute__((ext_vector_type(8)));
typedef float  f32x4  __attribute__((ext_vector_type(4)));
typedef float  f32x16 __attribute__((ext_vector_type(16)));
typedef unsigned int u32x4 __attribute__((ext_vector_type(4)));

#if __has_builtin(__builtin_amdgcn_exp2f)
#define EXP2(x) __builtin_amdgcn_exp2f(x)
#else
#define EXP2(x) exp2f(x)
#endif

static __device__ __forceinline__ unsigned int pk2(float lo, float hi) {
    unsigned short a = __builtin_bit_cast(unsigned short, (__bf16)lo);
    unsigned short b = __builtin_bit_cast(unsigned short, (__bf16)hi);
    return ((unsigned int)b << 16) | a;
}

static __device__ __forceinline__ __hip_bfloat16 bfc(float x) {
    return __float2bfloat16(x);
}

// ---------------- 1. prep: W transpose+cvt, X cvt ----------------
__global__ __launch_bounds__(256) void prep(
    const float* __restrict__ Wq,
    const float* __restrict__ Wk,
    const float* __restrict__ Wv,
    const float* __restrict__ xq,
    const float* __restrict__ xk,
    const float* __restrict__ xv,
    __hip_bfloat16* __restrict__ Wt,
    __hip_bfloat16* __restrict__ Xbq,
    __hip_bfloat16* __restrict__ Xbk,
    __hip_bfloat16* __restrict__ Xbv)
{
    int bid = blockIdx.x;
    if (bid < 1728) {
        __shared__ __hip_bfloat16 tile[32][33];
        int mat = bid / 576;
        int t   = bid - mat * 576;
        int tr  = t / 24, tc = t - (t / 24) * 24;
        const float* W = (mat == 0) ? Wq : (mat == 1) ? Wk : Wv;
        __hip_bfloat16* O = Wt + (size_t)mat * DMODEL * DMODEL;
        int tx = threadIdx.x & 31, ty = threadIdx.x >> 5;
#pragma unroll
        for (int i = 0; i < 32; i += 8)
            tile[ty + i][tx] = __float2bfloat16(W[(size_t)(tr * 32 + ty + i) * DMODEL + tc * 32 + tx]);
        __syncthreads();
#pragma unroll
        for (int i = 0; i < 32; i += 8)
            O[(size_t)(tc * 32 + ty + i) * DMODEL + tr * 32 + tx] = tile[tx][ty + i];
    } else {
        int b2  = bid - 1728;                 // 0..9215
        int mat = b2 / 3072;
        int r   = b2 - mat * 3072;
        const float* X = (mat == 0) ? xq : (mat == 1) ? xk : xv;
        __hip_bfloat16* O = (mat == 0) ? Xbq : (mat == 1) ? Xbk : Xbv;
        size_t off = (size_t)r * 2048 + threadIdx.x * 8;
        float4 f0 = *(const float4*)(X + off);
        float4 f1 = *(const float4*)(X + off + 4);
        unsigned int w0 = pk2(f0.x, f0.y), w1 = pk2(f0.z, f0.w);
        unsigned int w2 = pk2(f1.x, f1.y), w3 = pk2(f1.z, f1.w);
        u32x4 pv; pv[0] = w0; pv[1] = w1; pv[2] = w2; pv[3] = w3;
        *(u32x4*)(O + off) = pv;
    }
}

// ---------------- 2. QKV projection: phase-interleaved, counted vmcnt --------
// LDS chunk (row r, slot s of 4x16B) holds logical k-chunk s^((r>>1)&3).
// gload_lds dest = linear tid*16B; global source col pre-swizzled to match.
// Frag reads: slot = quad^((l16>>1)&3) — per-16-lane batches hit all 32 banks.
__global__ __launch_bounds__(512, 4) void qkv_proj(
    const __hip_bfloat16* __restrict__ Xbq,
    const __hip_bfloat16* __restrict__ Xbk,
    const __hip_bfloat16* __restrict__ Xbv,
    const __hip_bfloat16* __restrict__ Wt,
    const float* __restrict__ bq,
    const float* __restrict__ bk,
    const float* __restrict__ bv,
    __hip_bfloat16* __restrict__ Qr,
    __hip_bfloat16* __restrict__ Kr,
    __hip_bfloat16* __restrict__ Vt)
{
    __shared__ __hip_bfloat16 Abuf[3][8192];   // 3 x 16 KiB
    __shared__ __hip_bfloat16 Bbuf[2][4096];   // 2 x  8 KiB   (total 64 KiB)

    int tid  = threadIdx.x;
    int w    = tid >> 6, lane = tid & 63;
    int l16  = lane & 15, quad = lane >> 4;
    int wm   = w >> 1, wn = w & 1;             // 4M x 2N waves

    int xcd = blockIdx.x & 7, s = blockIdx.x >> 3;
    int nt  = s % 6;
    int idx = (s / 6) * 8 + xcd;               // 0..95
    int mat = idx >> 5, mt = idx & 31;
    int m0  = mt * 256, n0 = nt * 128;

    const __hip_bfloat16* X = (mat == 0) ? Xbq : (mat == 1) ? Xbk : Xbv;
    const __hip_bfloat16* W = Wt + (size_t)mat * DMODEL * DMODEL;
    const float* bias       = (mat == 0) ? bq : (mat == 1) ? bk : bv;

    // staging source: row sr = tid>>2, pre-swizzled col chunk
    int sr = tid >> 2;
    int sc = ((tid & 3) ^ ((tid >> 3) & 3)) * 8;
    const __hip_bfloat16* ga0 = X + (size_t)(m0 + sr) * DMODEL + sc;
    const __hip_bfloat16* ga1 = X + (size_t)(m0 + 128 + sr) * DMODEL + sc;
    const __hip_bfloat16* gb  = W + (size_t)(n0 + sr) * DMODEL + sc;

#define GLD(gp_, lp_) __builtin_amdgcn_global_load_lds(                        \
        (const __attribute__((address_space(1))) void*)(gp_),                  \
        (__attribute__((address_space(3))) void*)(lp_), 16, 0, 0)

    // frag read offsets: swizzled slot, lane-constant
    int swz  = (quad ^ ((l16 >> 1) & 3)) * 8;
    int aoff = (wm * 64 + l16) * 32 + swz;
    int boff = (wn * 64 + l16) * 32 + swz;

    f32x4 acc[4][4] = {};

    GLD(gb,       &Bbuf[0][tid * 8]);
    GLD(ga0,      &Abuf[0][tid * 8]);
    GLD(ga1,      &Abuf[0][4096 + tid * 8]);
    GLD(ga0 + 32, &Abuf[1][tid * 8]);
    GLD(ga1 + 32, &Abuf[1][4096 + tid * 8]);
    asm volatile("s_waitcnt vmcnt(2)" ::: "memory");
    asm volatile("s_barrier" ::: "memory");

    int abuf = 0, bbuf = 0, abS = 2;
    const __hip_bfloat16* gbS  = gb  + 32;
    const __hip_bfloat16* ga0S = ga0 + 64;
    const __hip_bfloat16* ga1S = ga1 + 64;

    for (int kt = 0; kt < 24; ++kt) {
        const __hip_bfloat16* LA = Abuf[abuf];
        const __hip_bfloat16* LB = Bbuf[bbuf];

        bf16x8 a[4], bA[2];
#pragma unroll
        for (int m_ = 0; m_ < 4; ++m_)
            a[m_] = *(const bf16x8*)&LA[aoff + m_ * 512];
        bA[0] = *(const bf16x8*)&LB[boff];
        bA[1] = *(const bf16x8*)&LB[boff + 512];

        if (kt < 23) { GLD(gbS, &Bbuf[bbuf ^ 1][tid * 8]); gbS += 32; }
        if (kt < 22) {
            GLD(ga0S, &Abuf[abS][tid * 8]);
            GLD(ga1S, &Abuf[abS][4096 + tid * 8]);
            ga0S += 32; ga1S += 32;
        }

        asm volatile("s_barrier" ::: "memory");
        __builtin_amdgcn_s_setprio(1);
#pragma unroll
        for (int m_ = 0; m_ < 4; ++m_) {
            acc[m_][0] = __builtin_amdgcn_mfma_f32_16x16x32_bf16(a[m_], bA[0], acc[m_][0], 0, 0, 0);
            acc[m_][1] = __builtin_amdgcn_mfma_f32_16x16x32_bf16(a[m_], bA[1], acc[m_][1], 0, 0, 0);
        }
        __builtin_amdgcn_s_setprio(0);
        asm volatile("s_barrier" ::: "memory");

        bf16x8 bB[2];
        bB[0] = *(const bf16x8*)&LB[boff + 1024];
        bB[1] = *(const bf16x8*)&LB[boff + 1536];

        if (kt < 22) asm volatile("s_waitcnt vmcnt(2)" ::: "memory");
        else         asm volatile("s_waitcnt vmcnt(0)" ::: "memory");
        asm volatile("s_barrier" ::: "memory");
        __builtin_amdgcn_s_setprio(1);
#pragma unroll
        for (int m_ = 0; m_ < 4; ++m_) {
            acc[m_][2] = __builtin_amdgcn_mfma_f32_16x16x32_bf16(a[m_], bB[0], acc[m_][2], 0, 0, 0);
            acc[m_][3] = __builtin_amdgcn_mfma_f32_16x16x32_bf16(a[m_], bB[1], acc[m_][3], 0, 0, 0);
        }
        __builtin_amdgcn_s_setprio(0);
        asm volatile("s_barrier" ::: "memory");

        abuf = (abuf == 2) ? 0 : abuf + 1;
        abS  = (abS  == 2) ? 0 : abS  + 1;
        bbuf ^= 1;
    }
#undef GLD

    // epilogue — j innermost so the 4 stores per row cover 128 contiguous bytes
    int colb = n0 + wn * 64 + l16;
    float bc0 = bias[colb];
    float bc1 = bias[colb + 16];
    float bc2 = bias[colb + 32];
    float bc3 = bias[colb + 48];
    if (mat == 0) {
#pragma unroll
        for (int i = 0; i < 4; ++i) {
            int row0 = m0 + wm * 64 + i * 16 + quad * 4;
#pragma unroll
            for (int r = 0; r < 4; ++r) {
                __hip_bfloat16* p = Qr + (size_t)(row0 + r) * DMODEL + colb;
                p[0]  = bfc((acc[i][0][r] + bc0) * QSCALE);
                p[16] = bfc((acc[i][1][r] + bc1) * QSCALE);
                p[32] = bfc((acc[i][2][r] + bc2) * QSCALE);
                p[48] = bfc((acc[i][3][r] + bc3) * QSCALE);
            }
        }
    } else if (mat == 1) {
#pragma unroll
        for (int i = 0; i < 4; ++i) {
            int row0 = m0 + wm * 64 + i * 16 + quad * 4;
#pragma unroll
            for (int r = 0; r < 4; ++r) {
                __hip_bfloat16* p = Kr + (size_t)(row0 + r) * DMODEL + colb;
                p[0]  = bfc(acc[i][0][r] + bc0);
                p[16] = bfc(acc[i][1][r] + bc1);
                p[32] = bfc(acc[i][2][r] + bc2);
                p[48] = bfc(acc[i][3][r] + bc3);
            }
        }
    } else {
#pragma unroll
        for (int j = 0; j < 4; ++j) {
            int col = colb + j * 16;
            float bc = (j == 0) ? bc0 : (j == 1) ? bc1 : (j == 2) ? bc2 : bc3;
            int h = col / 48, dh = col - h * 48;
#pragma unroll
            for (int i = 0; i < 4; ++i) {
                int row0 = m0 + wm * 64 + i * 16 + quad * 4;
                int bb = row0 >> 11, s0 = row0 & 2047;
                unsigned int lo = pk2(acc[i][j][0] + bc, acc[i][j][1] + bc);
                unsigned int hi = pk2(acc[i][j][2] + bc, acc[i][j][3] + bc);
                uint2 pw; pw.x = lo; pw.y = hi;
                *(uint2*)(Vt + ((size_t)(bb * NHEAD + h) * DHEAD + dh) * SEQ + s0) = pw;
            }
        }
    }
}

// ---------------- 3. MFMA causal flash attention, 32x32 shape ------------
// Per wave: 32 q rows. QK^T: S[k][q] via mfma_32x32x16 (A=K, B=Q^T, 3 dh-slices).
// S frag: q=lane&31, k=(reg&3)+8*(reg>>2)+4*half. PV A-frag k=8*half+j via
// v_permlane32_swap_b32. V^T row 48 = ones -> PV dtile2 col 48 = row sum.
__global__ __launch_bounds__(256, 3) void attn(
    const __hip_bfloat16* __restrict__ Qr,
    const __hip_bfloat16* __restrict__ Kr,
    const __hip_bfloat16* __restrict__ Vt,
    __hip_bfloat16* __restrict__ Ao)
{
    __shared__ __hip_bfloat16 Ks[2][64][64];   // 16 KiB (slots 0..5 = dh 0..47)
    __shared__ __hip_bfloat16 Vs[2][64][64];   // 16 KiB (rows 0..47 = V^T, 48 = ones, 49..63 = 0)

    int tid  = threadIdx.x;
    int w    = tid >> 6, lane = tid & 63;
    int l31  = lane & 31;
    int half = lane >> 5;
    bool hb  = half != 0;
    int bh   = blockIdx.x & 63;
    int qt   = 15 - (blockIdx.x >> 6);         // heavy q-tiles dispatch first
    int q0   = qt * 128;
    int b    = bh >> 4, h = bh & 15;           // h = head
    size_t rowbase = (size_t)b * SEQ;

    const __hip_bfloat16* Qp = Qr + rowbase * DMODEL + h * DHEAD;
    const __hip_bfloat16* Kp = Kr + rowbase * DMODEL + h * DHEAD;
    const __hip_bfloat16* Vp = Vt + (size_t)bh * DHEAD * SEQ;

    // init Vs pad rows 48..63 (row 48 = ones for the lsum column, rest 0)
    {
        int zbuf = tid >> 7, zi = tid & 127;
        int zr = 48 + (zi >> 3), zsl = zi & 7;
        unsigned int v = (zr == 48) ? 0x3F803F80u : 0u;
        u32x4 pv; pv[0] = v; pv[1] = v; pv[2] = v; pv[3] = v;
        *(u32x4*)&Vs[zbuf][zr][(zsl ^ (zr & 7)) * 8] = pv;
    }

    // Q B-frags: B[col=q=l31][dh = t*16 + half*8 + j], 3 dh-slices
    int q0w = q0 + w * 32;
    bf16x8 bQ0, bQ1, bQ2;
    {
        const __hip_bfloat16* qp = Qp + (size_t)(q0w + l31) * DMODEL + half * 8;
        bQ0 = *(const bf16x8*)(qp);
        bQ1 = *(const bf16x8*)(qp + 16);
        bQ2 = *(const bf16x8*)(qp + 32);
    }

    // staging chunk maps: K = 384 chunks (64r x 6 slots), V = 384 (48r x 8 slots)
    int kr1 = tid / 6,          ksl1 = tid - kr1 * 6;
    int kr2 = (tid + 256) / 6,  ksl2 = (tid + 256) - kr2 * 6;
    int vd1 = tid >> 3,         vsl1 = tid & 7;
    int vd2 = (tid + 256) >> 3, vsl2 = tid & 7;
    int kso1 = (ksl1 ^ (kr1 & 7)) * 8;
    int kso2 = (ksl2 ^ (kr2 & 7)) * 8;
    int vso1 = (vsl1 ^ (vd1 & 7)) * 8;
    int vso2 = (vsl2 ^ (vd2 & 7)) * 8;

    const __hip_bfloat16* pK1 = Kp + (size_t)kr1 * DMODEL + ksl1 * 8;
    const __hip_bfloat16* pK2 = Kp + (size_t)kr2 * DMODEL + ksl2 * 8;
    const __hip_bfloat16* pV1 = Vp + (size_t)vd1 * SEQ + vsl1 * 8;
    const __hip_bfloat16* pV2 = Vp + (size_t)vd2 * SEQ + vsl2 * 8;

    uint4 kv1, kv2, vv1, vv2;

#define ATTN_LOAD() {                                                           \
        kv1 = *(const uint4*)pK1;                                               \
        vv1 = *(const uint4*)pV1;                                               \
        if (tid < 128) {                                                        \
            kv2 = *(const uint4*)pK2;                                           \
            vv2 = *(const uint4*)pV2;                                           \
        }                                                                       \
        pK1 += 64 * DMODEL; pK2 += 64 * DMODEL; pV1 += 64; pV2 += 64; }

#define ATTN_STORE(buf_) {                                                      \
        *(uint4*)&Ks[buf_][kr1][kso1] = kv1;                                    \
        *(uint4*)&Vs[buf_][vd1][vso1] = vv1;                                    \
        if (tid < 128) {                                                        \
            *(uint4*)&Ks[buf_][kr2][kso2] = kv2;                                \
            *(uint4*)&Vs[buf_][vd2][vso2] = vv2;                                \
        } }

#define MFMA32(A_, B_, C_) __builtin_amdgcn_mfma_f32_32x32x16_bf16(A_, B_, C_, 0, 0, 0)

    f32x16 O1 = {}, O2 = {};
    const f32x16 z16 = {};

    int ktmax = 2 * qt + 1;                    // >= 1 always
    ATTN_LOAD();
    ATTN_STORE(0);
    ATTN_LOAD();
    __syncthreads();

    for (int kt = 0; kt <= ktmax; ++kt) {
        int buf = kt & 1;
        int k0  = kt * 64;
        if (kt + 1 <= ktmax) ATTN_STORE(buf ^ 1);
        if (kt + 2 <= ktmax) ATTN_LOAD();

#pragma unroll
        for (int kc = 0; kc < 2; ++kc) {
            int kbase = k0 + kc * 32;
            if (kbase <= q0w + 31) {           // wave-uniform active guard
                // ---- QK^T: A = K rows (kbase..+31), 3 dh-slices ----
                int krow = kc * 32 + l31;
                int ksw  = krow & 7;
                bf16x8 aK0 = *(const bf16x8*)&Ks[buf][krow][((0 + half) ^ ksw) * 8];
                bf16x8 aK1 = *(const bf16x8*)&Ks[buf][krow][((2 + half) ^ ksw) * 8];
                bf16x8 aK2 = *(const bf16x8*)&Ks[buf][krow][((4 + half) ^ ksw) * 8];

                __builtin_amdgcn_s_setprio(1);
                f32x16 s_;
                s_ = MFMA32(aK0, bQ0, z16);
                s_ = MFMA32(aK1, bQ1, s_);
                s_ = MFMA32(aK2, bQ2, s_);
                __builtin_amdgcn_s_setprio(0);

                // ---- causal mask (boundary tiles only) ----
                if (kbase + 31 > q0w) {
                    int qg = q0w + l31;
                    int kb = kbase + (hb ? 4 : 0);
#pragma unroll
                    for (int r = 0; r < 16; ++r) {
                        int kl = (r & 3) + 8 * (r >> 2);
                        if (kb + kl > qg) s_[r] = -1e30f;
                    }
                }

                // ---- exp2 (raw v_exp_f32) + pack ----
                unsigned int p0, p1, p2, p3, p4, p5, p6, p7;
                {
                    float e0 = EXP2(s_[0]),  e1 = EXP2(s_[1]);
                    float e2 = EXP2(s_[2]),  e3 = EXP2(s_[3]);
                    float e4 = EXP2(s_[4]),  e5 = EXP2(s_[5]);
                    float e6 = EXP2(s_[6]),  e7 = EXP2(s_[7]);
                    float e8 = EXP2(s_[8]),  e9 = EXP2(s_[9]);
                    float ea = EXP2(s_[10]), eb = EXP2(s_[11]);
                    float ec = EXP2(s_[12]), ed = EXP2(s_[13]);
                    float ee = EXP2(s_[14]), ef = EXP2(s_[15]);
                    p0 = pk2(e0, e1); p1 = pk2(e2, e3);
                    p2 = pk2(e4, e5); p3 = pk2(e6, e7);
                    p4 = pk2(e8, e9); p5 = pk2(ea, eb);
                    p6 = pk2(ec, ed); p7 = pk2(ee, ef);
                }

                // ---- half-exchange -> PV A-frags ----
                u32x4 F0w, F1w;
#if __has_builtin(__builtin_amdgcn_permlane32_swap)
                {
                    typedef unsigned int u32x2 __attribute__((ext_vector_type(2)));
                    u32x2 r0 = __builtin_amdgcn_permlane32_swap(p0, p2, false, false);
                    u32x2 r1 = __builtin_amdgcn_permlane32_swap(p1, p3, false, false);
                    u32x2 r2 = __builtin_amdgcn_permlane32_swap(p4, p6, false, false);
                    u32x2 r3 = __builtin_amdgcn_permlane32_swap(p5, p7, false, false);
                    F0w[0] = r0[0]; F0w[1] = r1[0]; F0w[2] = r0[1]; F0w[3] = r1[1];
                    F1w[0] = r2[0]; F1w[1] = r3[0]; F1w[2] = r2[1]; F1w[3] = r3[1];
                }
#else
                {
                    unsigned int sx0 = __shfl_xor(hb ? p0 : p2, 32, 64);
                    unsigned int sx1 = __shfl_xor(hb ? p1 : p3, 32, 64);
                    unsigned int sx2 = __shfl_xor(hb ? p4 : p6, 32, 64);
                    unsigned int sx3 = __shfl_xor(hb ? p5 : p7, 32, 64);
                    F0w[0] = hb ? sx0 : p0;  F0w[1] = hb ? sx1 : p1;
                    F0w[2] = hb ? p2  : sx0; F0w[3] = hb ? p3  : sx1;
                    F1w[0] = hb ? sx2 : p4;  F1w[1] = hb ? sx3 : p5;
                    F1w[2] = hb ? p6  : sx2; F1w[3] = hb ? p7  : sx3;
                }
#endif
                bf16x8 F0 = __builtin_bit_cast(bf16x8, F0w);
                bf16x8 F1 = __builtin_bit_cast(bf16x8, F1w);

                // ---- PV: B[col=d][k], d-tiles {0..31}, {32..63 (48=ones)} ----
                int vr0 = l31, vr1 = 32 + l31;
                int vw0 = vr0 & 7, vw1 = vr1 & 7;
                bf16x8 bV00 = *(const bf16x8*)&Vs[buf][vr0][((kc * 4 + 0 + half) ^ vw0) * 8];
                bf16x8 bV01 = *(const bf16x8*)&Vs[buf][vr1][((kc * 4 + 0 + half) ^ vw1) * 8];
                bf16x8 bV10 = *(const bf16x8*)&Vs[buf][vr0][((kc * 4 + 2 + half) ^ vw0) * 8];
                bf16x8 bV11 = *(const bf16x8*)&Vs[buf][vr1][((kc * 4 + 2 + half) ^ vw1) * 8];

                __builtin_amdgcn_s_setprio(1);
                O1 = MFMA32(F0, bV00, O1);
                O2 = MFMA32(F0, bV01, O2);
                O1 = MFMA32(F1, bV10, O1);
                O2 = MFMA32(F1, bV11, O2);
                __builtin_amdgcn_s_setprio(0);
            }
        }

        asm volatile("s_waitcnt lgkmcnt(0)" ::: "memory");
        __builtin_amdgcn_s_barrier();
        asm volatile("" ::: "memory");
    }

    // epilogue: lsum lives in O2 col 48 (lane l31==16 of own half)
    int lsrc = (lane & 32) + 16;
#pragma unroll
    for (int r = 0; r < 16; ++r) {
        float lden = __shfl(O2[r], lsrc, 64);
        float linv = 1.f / lden;
        int q = q0w + (r & 3) + 8 * (r >> 2) + (hb ? 4 : 0);
        size_t g = (rowbase + q) * DMODEL + h * DHEAD;
        Ao[g + l31] = __float2bfloat16(O1[r] * linv);
        if (l31 < 16)
            Ao[g + 32 + l31] = __float2bfloat16(O2[r] * linv);
    }
#undef ATTN_LOAD
#undef ATTN_STORE
#undef MFMA32
}

// ---------------- 4. LayerNorm (eps = 1e-3), wave-per-row, fp32 out ----------------
__global__ __launch_bounds__(256) void lnorm(
    const __hip_bfloat16* __restrict__ Ao,
    const float* __restrict__ gamma,
    const float* __restrict__ beta,
    float* __restrict__ out)
{
    int tid = threadIdx.x;
    int wv  = tid >> 6, ln = tid & 63;
    int row = blockIdx.x * 4 + wv;
    size_t base = (size_t)row * DMODEL + ln * 4;

    ushort4 u0 = *(const ushort4*)(Ao + base);
    ushort4 u1 = *(const ushort4*)(Ao + base + 256);
    ushort4 u2 = *(const ushort4*)(Ao + base + 512);
    float x0, x1, x2, x3, x4, x5, x6, x7, x8, x9, xa, xb;
    { unsigned int v = (unsigned int)u0.x << 16; __builtin_memcpy(&x0, &v, 4); }
    { unsigned int v = (unsigned int)u0.y << 16; __builtin_memcpy(&x1, &v, 4); }
    { unsigned int v = (unsigned int)u0.z << 16; __builtin_memcpy(&x2, &v, 4); }
    { unsigned int v = (unsigned int)u0.w << 16; __builtin_memcpy(&x3, &v, 4); }
    { unsigned int v = (unsigned int)u1.x << 16; __builtin_memcpy(&x4, &v, 4); }
    { unsigned int v = (unsigned int)u1.y << 16; __builtin_memcpy(&x5, &v, 4); }
    { unsigned int v = (unsigned int)u1.z << 16; __builtin_memcpy(&x6, &v, 4); }
    { unsigned int v = (unsigned int)u1.w << 16; __builtin_memcpy(&x7, &v, 4); }
    { unsigned int v = (unsigned int)u2.x << 16; __builtin_memcpy(&x8, &v, 4); }
    { unsigned int v = (unsigned int)u2.y << 16; __builtin_memcpy(&x9, &v, 4); }
    { unsigned int v = (unsigned int)u2.z << 16; __builtin_memcpy(&xa, &v, 4); }
    { unsigned int v = (unsigned int)u2.w << 16; __builtin_memcpy(&xb, &v, 4); }

    float s = ((x0 + x1) + (x2 + x3)) + ((x4 + x5) + (x6 + x7)) + ((x8 + x9) + (xa + xb));
    float q = ((x0*x0 + x1*x1) + (x2*x2 + x3*x3)) + ((x4*x4 + x5*x5) + (x6*x6 + x7*x7))
            + ((x8*x8 + x9*x9) + (xa*xa + xb*xb));
#pragma unroll
    for (int m = 32; m >= 1; m >>= 1) {
        s += __shfl_xor(s, m, 64);
        q += __shfl_xor(q, m, 64);
    }
    float mu  = s * (1.f / 768.f);
    float var = q * (1.f / 768.f) - mu * mu;
    float rstd = rsqrtf(var + 1e-3f);

    float4 g0 = *(const float4*)(gamma + ln * 4);
    float4 g1 = *(const float4*)(gamma + ln * 4 + 256);
    float4 g2 = *(const float4*)(gamma + ln * 4 + 512);
    float4 e0 = *(const float4*)(beta + ln * 4);
    float4 e1 = *(const float4*)(beta + ln * 4 + 256);
    float4 e2 = *(const float4*)(beta + ln * 4 + 512);
    float4 o0, o1, o2;
    o0.x = (x0 - mu) * rstd * g0.x + e0.x;
    o0.y = (x1 - mu) * rstd * g0.y + e0.y;
    o0.z = (x2 - mu) * rstd * g0.z + e0.z;
    o0.w = (x3 - mu) * rstd * g0.w + e0.w;
    o1.x = (x4 - mu) * rstd * g1.x + e1.x;
    o1.y = (x5 - mu) * rstd * g1.y + e1.y;
    o1.z = (x6 - mu) * rstd * g1.z + e1.z;
    o1.w = (x7 - mu) * rstd * g1.w + e1.w;
    o2.x = (x8 - mu) * rstd * g2.x + e2.x;
    o2.y = (x9 - mu) * rstd * g2.y + e2.y;
    o2.z = (xa - mu) * rstd * g2.z + e2.z;
    o2.w = (xb - mu) * rstd * g2.w + e2.w;
    *(float4*)(out + base)       = o0;
    *(float4*)(out + base + 256) = o1;
    *(float4*)(out + base + 512) = o2;
}

extern "C" void kernel_launch(void* const* d_in, const int* in_sizes, int n_in,
                              void* d_out, int out_size, void* d_ws, size_t ws_size,
                              hipStream_t stream) {
    const float* q     = (const float*)d_in[0];
    const float* k     = (const float*)d_in[1];
    const float* v     = (const float*)d_in[2];
    const float* Wq    = (const float*)d_in[3];
    const float* bq    = (const float*)d_in[4];
    const float* Wk    = (const float*)d_in[5];
    const float* bk    = (const float*)d_in[6];
    const float* Wv    = (const float*)d_in[7];
    const float* bv    = (const float*)d_in[8];
    const float* gamma = (const float*)d_in[9];
    const float* beta  = (const float*)d_in[10];

    char* basep = (char*)d_ws;
    __hip_bfloat16* Wt = (__hip_bfloat16*)basep;
    __hip_bfloat16* Qr = (__hip_bfloat16*)(basep + 3538944);
    __hip_bfloat16* Kr = Qr + (size_t)NROWS * DMODEL;
    __hip_bfloat16* Vt = Kr + (size_t)NROWS * DMODEL;
    __hip_bfloat16* Ao = Vt + (size_t)NROWS * DMODEL;
    float* out = (float*)d_out;

    __hip_bfloat16* Xbq = (__hip_bfloat16*)d_out;
    __hip_bfloat16* Xbk = Xbq + (size_t)NROWS * DMODEL;
    __hip_bfloat16* Xbv = Ao;

    hipLaunchKernelGGL(prep, dim3(10944), dim3(256), 0, stream,
                       Wq, Wk, Wv, q, k, v, Wt, Xbq, Xbk, Xbv);
    hipLaunchKernelGGL(qkv_proj, dim3(576), dim3(512), 0, stream,
                       Xbq, Xbk, Xbv, Wt, bq, bk, bv, Qr, Kr, Vt);
    hipLaunchKernelGGL(attn, dim3(1024), dim3(256), 0, stream, Qr, Kr, Vt, Ao);
    hipLaunchKernelGGL(lnorm, dim3(2048), dim3(256), 0, stream, Ao, gamma, beta, out);
}

// Round 9
// 225.356 us; speedup vs baseline: 1.7460x; 1.0357x over previous
//
#include <hip/hip_runtime.h>
#include <hip/hip_bf16.h>

// Fused MHA block. B=4, S=2048, D=768, H=16, DH=48, causal, LayerNorm(eps=1e-3).
// FP32 harness buffers; bf16 MFMA internally (threshold is bf16-lenient, 2% rel).
//
// Pipeline:
//   1. prep     : Wt[n][k] = bf16(W[k][n])  +  Xb = bf16(x) for q,k,v.
//   2. qkv_proj : R9: 128x128 tile, 4 waves, 4 blocks/CU (40KB LDS), ONE
//                 barrier per k-tile (16-MFMA cluster), A 3-buf 2-ahead /
//                 B 2-buf 1-ahead, vmcnt(2) counted wait, both-sides LDS
//                 swizzle (R8, 0 conflicts), j-innermost epilogue.
//   3. attn     : flash attn on 32x32 MFMA (R7: raw exp2, permlane32_swap).
//   4. lnorm    : wave-per-row LayerNorm, no LDS/syncthreads, fp32 out.

#define DMODEL 768
#define NHEAD  16
#define DHEAD  48
#define SEQ    2048
#define NBATCH 4
#define NROWS  (NBATCH * SEQ)                 // 8192
// Q prescale: 1/sqrt(48) * log2(e)  -> softmax = single v_exp_f32 (2^x)
#define QSCALE (0.14433756729740643f * 1.4426950408889634f)

typedef __bf16 bf16x8 __attribute__((ext_vector_type(8)));
typedef float  f32x4  __attribute__((ext_vector_type(4)));
typedef float  f32x16 __attribute__((ext_vector_type(16)));
typedef unsigned int u32x4 __attribute__((ext_vector_type(4)));

#if __has_builtin(__builtin_amdgcn_exp2f)
#define EXP2(x) __builtin_amdgcn_exp2f(x)
#else
#define EXP2(x) exp2f(x)
#endif

static __device__ __forceinline__ unsigned int pk2(float lo, float hi) {
    unsigned short a = __builtin_bit_cast(unsigned short, (__bf16)lo);
    unsigned short b = __builtin_bit_cast(unsigned short, (__bf16)hi);
    return ((unsigned int)b << 16) | a;
}

static __device__ __forceinline__ __hip_bfloat16 bfc(float x) {
    return __float2bfloat16(x);
}

// ---------------- 1. prep: W transpose+cvt, X cvt ----------------
__global__ __launch_bounds__(256) void prep(
    const float* __restrict__ Wq,
    const float* __restrict__ Wk,
    const float* __restrict__ Wv,
    const float* __restrict__ xq,
    const float* __restrict__ xk,
    const float* __restrict__ xv,
    __hip_bfloat16* __restrict__ Wt,
    __hip_bfloat16* __restrict__ Xbq,
    __hip_bfloat16* __restrict__ Xbk,
    __hip_bfloat16* __restrict__ Xbv)
{
    int bid = blockIdx.x;
    if (bid < 1728) {
        __shared__ __hip_bfloat16 tile[32][33];
        int mat = bid / 576;
        int t   = bid - mat * 576;
        int tr  = t / 24, tc = t - (t / 24) * 24;
        const float* W = (mat == 0) ? Wq : (mat == 1) ? Wk : Wv;
        __hip_bfloat16* O = Wt + (size_t)mat * DMODEL * DMODEL;
        int tx = threadIdx.x & 31, ty = threadIdx.x >> 5;
#pragma unroll
        for (int i = 0; i < 32; i += 8)
            tile[ty + i][tx] = __float2bfloat16(W[(size_t)(tr * 32 + ty + i) * DMODEL + tc * 32 + tx]);
        __syncthreads();
#pragma unroll
        for (int i = 0; i < 32; i += 8)
            O[(size_t)(tc * 32 + ty + i) * DMODEL + tr * 32 + tx] = tile[tx][ty + i];
    } else {
        int b2  = bid - 1728;                 // 0..9215
        int mat = b2 / 3072;
        int r   = b2 - mat * 3072;
        const float* X = (mat == 0) ? xq : (mat == 1) ? xk : xv;
        __hip_bfloat16* O = (mat == 0) ? Xbq : (mat == 1) ? Xbk : Xbv;
        size_t off = (size_t)r * 2048 + threadIdx.x * 8;
        float4 f0 = *(const float4*)(X + off);
        float4 f1 = *(const float4*)(X + off + 4);
        unsigned int w0 = pk2(f0.x, f0.y), w1 = pk2(f0.z, f0.w);
        unsigned int w2 = pk2(f1.x, f1.y), w3 = pk2(f1.z, f1.w);
        u32x4 pv; pv[0] = w0; pv[1] = w1; pv[2] = w2; pv[3] = w3;
        *(u32x4*)(O + off) = pv;
    }
}

// ---------------- 2. QKV projection: 128x128, 1 barrier/k-tile ---------------
// LDS chunk (row r, slot s of 4x16B) holds logical k-chunk s^((r>>1)&3);
// gload_lds dest linear, global source col pre-swizzled (R8, proven 0-conflict).
// A: 3 bufs (stage kt+2), B: 2 bufs (stage kt+1). Per tile: 8 ds_read_b128,
// 4 global_load_lds, 16 MFMA, lgkmcnt(0)+vmcnt(2), 1 s_barrier.
__global__ __launch_bounds__(256, 4) void qkv_proj(
    const __hip_bfloat16* __restrict__ Xbq,
    const __hip_bfloat16* __restrict__ Xbk,
    const __hip_bfloat16* __restrict__ Xbv,
    const __hip_bfloat16* __restrict__ Wt,
    const float* __restrict__ bq,
    const float* __restrict__ bk,
    const float* __restrict__ bv,
    __hip_bfloat16* __restrict__ Qr,
    __hip_bfloat16* __restrict__ Kr,
    __hip_bfloat16* __restrict__ Vt)
{
    __shared__ __hip_bfloat16 Abuf[3][4096];   // 3 x 8 KiB
    __shared__ __hip_bfloat16 Bbuf[2][4096];   // 2 x 8 KiB   (total 40 KiB)

    int tid  = threadIdx.x;
    int w    = tid >> 6, lane = tid & 63;
    int l16  = lane & 15, quad = lane >> 4;
    int wm   = w >> 1, wn = w & 1;             // 2M x 2N waves, 64x64 each

    // XCD swizzle: 6 nt-blocks of one (mat,mt) share bid%8 -> same XCD L2.
    int xcd = blockIdx.x & 7, s = blockIdx.x >> 3;
    int nt  = s % 6;
    int idx = (s / 6) * 8 + xcd;               // 0..191
    int mat = idx >> 6, mt = idx & 63;
    int m0  = mt * 128, n0 = nt * 128;

    const __hip_bfloat16* X = (mat == 0) ? Xbq : (mat == 1) ? Xbk : Xbv;
    const __hip_bfloat16* W = Wt + (size_t)mat * DMODEL * DMODEL;
    const float* bias       = (mat == 0) ? bq : (mat == 1) ? bk : bv;

    // staging: thread t owns chunks {t, t+256}; chunk c = (row c>>2, slot c&3),
    // logical k-chunk = slot ^ ((row>>1)&3). Chunk t+256 = same col, row+64.
    int sr = tid >> 2;
    int sc = ((tid & 3) ^ ((tid >> 3) & 3)) * 8;
    const __hip_bfloat16* ga = X + (size_t)(m0 + sr) * DMODEL + sc;
    const __hip_bfloat16* gb = W + (size_t)(n0 + sr) * DMODEL + sc;

#define GLD(gp_, lp_) __builtin_amdgcn_global_load_lds(                        \
        (const __attribute__((address_space(1))) void*)(gp_),                  \
        (__attribute__((address_space(3))) void*)(lp_), 16, 0, 0)
#define GLDB(t_, buf_) {                                                       \
        GLD(gb + (t_) * 32,               &Bbuf[buf_][tid * 8]);               \
        GLD(gb + 64 * DMODEL + (t_) * 32, &Bbuf[buf_][2048 + tid * 8]); }
#define GLDA(t_, buf_) {                                                       \
        GLD(ga + (t_) * 32,               &Abuf[buf_][tid * 8]);               \
        GLD(ga + 64 * DMODEL + (t_) * 32, &Abuf[buf_][2048 + tid * 8]); }

    // frag reads: swizzled slot, lane-constant (R8-verified involution)
    int swz  = (quad ^ ((l16 >> 1) & 3)) * 8;
    int aoff = (wm * 64 + l16) * 32 + swz;
    int boff = (wn * 64 + l16) * 32 + swz;

    f32x4 acc[4][4] = {};

    // prologue: B(0), A(0) landed; A(1) in flight
    GLDB(0, 0);
    GLDA(0, 0);
    GLDA(1, 1);
    asm volatile("s_waitcnt vmcnt(2)" ::: "memory");
    asm volatile("s_barrier" ::: "memory");

    int ab = 0, bb = 0;
    for (int kt = 0; kt < 24; ++kt) {
        const __hip_bfloat16* LA = Abuf[ab];
        const __hip_bfloat16* LB = Bbuf[bb];

        bf16x8 a[4], b[4];
#pragma unroll
        for (int i = 0; i < 4; ++i)
            a[i] = *(const bf16x8*)&LA[aoff + i * 512];
#pragma unroll
        for (int j = 0; j < 4; ++j)
            b[j] = *(const bf16x8*)&LB[boff + j * 512];

        if (kt < 23) GLDB(kt + 1, bb ^ 1);
        int aw = (ab == 0) ? 2 : ab - 1;       // (ab+2)%3
        if (kt < 22) GLDA(kt + 2, aw);

        __builtin_amdgcn_s_setprio(1);
#pragma unroll
        for (int i = 0; i < 4; ++i)
#pragma unroll
            for (int j = 0; j < 4; ++j)
                acc[i][j] = __builtin_amdgcn_mfma_f32_16x16x32_bf16(a[i], b[j], acc[i][j], 0, 0, 0);
        __builtin_amdgcn_s_setprio(0);

        if (kt < 23) {
            asm volatile("s_waitcnt lgkmcnt(0)" ::: "memory");
            if (kt < 22) asm volatile("s_waitcnt vmcnt(2)" ::: "memory");
            else         asm volatile("s_waitcnt vmcnt(0)" ::: "memory");
            asm volatile("s_barrier" ::: "memory");
        }

        ab = (ab == 2) ? 0 : ab + 1;
        bb ^= 1;
    }
#undef GLD
#undef GLDA
#undef GLDB

    // epilogue — j innermost so the 4 stores per row cover 128 contiguous bytes
    int colb = n0 + wn * 64 + l16;
    float bc0 = bias[colb];
    float bc1 = bias[colb + 16];
    float bc2 = bias[colb + 32];
    float bc3 = bias[colb + 48];
    if (mat == 0) {
#pragma unroll
        for (int i = 0; i < 4; ++i) {
            int row0 = m0 + wm * 64 + i * 16 + quad * 4;
#pragma unroll
            for (int r = 0; r < 4; ++r) {
                __hip_bfloat16* p = Qr + (size_t)(row0 + r) * DMODEL + colb;
                p[0]  = bfc((acc[i][0][r] + bc0) * QSCALE);
                p[16] = bfc((acc[i][1][r] + bc1) * QSCALE);
                p[32] = bfc((acc[i][2][r] + bc2) * QSCALE);
                p[48] = bfc((acc[i][3][r] + bc3) * QSCALE);
            }
        }
    } else if (mat == 1) {
#pragma unroll
        for (int i = 0; i < 4; ++i) {
            int row0 = m0 + wm * 64 + i * 16 + quad * 4;
#pragma unroll
            for (int r = 0; r < 4; ++r) {
                __hip_bfloat16* p = Kr + (size_t)(row0 + r) * DMODEL + colb;
                p[0]  = bfc(acc[i][0][r] + bc0);
                p[16] = bfc(acc[i][1][r] + bc1);
                p[32] = bfc(acc[i][2][r] + bc2);
                p[48] = bfc(acc[i][3][r] + bc3);
            }
        }
    } else {
#pragma unroll
        for (int j = 0; j < 4; ++j) {
            int col = colb + j * 16;
            float bc = (j == 0) ? bc0 : (j == 1) ? bc1 : (j == 2) ? bc2 : bc3;
            int h = col / 48, dh = col - h * 48;
#pragma unroll
            for (int i = 0; i < 4; ++i) {
                int row0 = m0 + wm * 64 + i * 16 + quad * 4;
                int bb2 = row0 >> 11, s0 = row0 & 2047;
                unsigned int lo = pk2(acc[i][j][0] + bc, acc[i][j][1] + bc);
                unsigned int hi = pk2(acc[i][j][2] + bc, acc[i][j][3] + bc);
                uint2 pw; pw.x = lo; pw.y = hi;
                *(uint2*)(Vt + ((size_t)(bb2 * NHEAD + h) * DHEAD + dh) * SEQ + s0) = pw;
            }
        }
    }
}

// ---------------- 3. MFMA causal flash attention, 32x32 shape ------------
// Per wave: 32 q rows. QK^T: S[k][q] via mfma_32x32x16 (A=K, B=Q^T, 3 dh-slices).
// S frag: q=lane&31, k=(reg&3)+8*(reg>>2)+4*half. PV A-frag k=8*half+j via
// v_permlane32_swap_b32. V^T row 48 = ones -> PV dtile2 col 48 = row sum.
__global__ __launch_bounds__(256, 3) void attn(
    const __hip_bfloat16* __restrict__ Qr,
    const __hip_bfloat16* __restrict__ Kr,
    const __hip_bfloat16* __restrict__ Vt,
    __hip_bfloat16* __restrict__ Ao)
{
    __shared__ __hip_bfloat16 Ks[2][64][64];   // 16 KiB (slots 0..5 = dh 0..47)
    __shared__ __hip_bfloat16 Vs[2][64][64];   // 16 KiB (rows 0..47 = V^T, 48 = ones, 49..63 = 0)

    int tid  = threadIdx.x;
    int w    = tid >> 6, lane = tid & 63;
    int l31  = lane & 31;
    int half = lane >> 5;
    bool hb  = half != 0;
    int bh   = blockIdx.x & 63;
    int qt   = 15 - (blockIdx.x >> 6);         // heavy q-tiles dispatch first
    int q0   = qt * 128;
    int b    = bh >> 4, h = bh & 15;           // h = head
    size_t rowbase = (size_t)b * SEQ;

    const __hip_bfloat16* Qp = Qr + rowbase * DMODEL + h * DHEAD;
    const __hip_bfloat16* Kp = Kr + rowbase * DMODEL + h * DHEAD;
    const __hip_bfloat16* Vp = Vt + (size_t)bh * DHEAD * SEQ;

    // init Vs pad rows 48..63 (row 48 = ones for the lsum column, rest 0)
    {
        int zbuf = tid >> 7, zi = tid & 127;
        int zr = 48 + (zi >> 3), zsl = zi & 7;
        unsigned int v = (zr == 48) ? 0x3F803F80u : 0u;
        u32x4 pv; pv[0] = v; pv[1] = v; pv[2] = v; pv[3] = v;
        *(u32x4*)&Vs[zbuf][zr][(zsl ^ (zr & 7)) * 8] = pv;
    }

    // Q B-frags: B[col=q=l31][dh = t*16 + half*8 + j], 3 dh-slices
    int q0w = q0 + w * 32;
    bf16x8 bQ0, bQ1, bQ2;
    {
        const __hip_bfloat16* qp = Qp + (size_t)(q0w + l31) * DMODEL + half * 8;
        bQ0 = *(const bf16x8*)(qp);
        bQ1 = *(const bf16x8*)(qp + 16);
        bQ2 = *(const bf16x8*)(qp + 32);
    }

    // staging chunk maps: K = 384 chunks (64r x 6 slots), V = 384 (48r x 8 slots)
    int kr1 = tid / 6,          ksl1 = tid - kr1 * 6;
    int kr2 = (tid + 256) / 6,  ksl2 = (tid + 256) - kr2 * 6;
    int vd1 = tid >> 3,         vsl1 = tid & 7;
    int vd2 = (tid + 256) >> 3, vsl2 = tid & 7;
    int kso1 = (ksl1 ^ (kr1 & 7)) * 8;
    int kso2 = (ksl2 ^ (kr2 & 7)) * 8;
    int vso1 = (vsl1 ^ (vd1 & 7)) * 8;
    int vso2 = (vsl2 ^ (vd2 & 7)) * 8;

    const __hip_bfloat16* pK1 = Kp + (size_t)kr1 * DMODEL + ksl1 * 8;
    const __hip_bfloat16* pK2 = Kp + (size_t)kr2 * DMODEL + ksl2 * 8;
    const __hip_bfloat16* pV1 = Vp + (size_t)vd1 * SEQ + vsl1 * 8;
    const __hip_bfloat16* pV2 = Vp + (size_t)vd2 * SEQ + vsl2 * 8;

    uint4 kv1, kv2, vv1, vv2;

#define ATTN_LOAD() {                                                           \
        kv1 = *(const uint4*)pK1;                                               \
        vv1 = *(const uint4*)pV1;                                               \
        if (tid < 128) {                                                        \
            kv2 = *(const uint4*)pK2;                                           \
            vv2 = *(const uint4*)pV2;                                           \
        }                                                                       \
        pK1 += 64 * DMODEL; pK2 += 64 * DMODEL; pV1 += 64; pV2 += 64; }

#define ATTN_STORE(buf_) {                                                      \
        *(uint4*)&Ks[buf_][kr1][kso1] = kv1;                                    \
        *(uint4*)&Vs[buf_][vd1][vso1] = vv1;                                    \
        if (tid < 128) {                                                        \
            *(uint4*)&Ks[buf_][kr2][kso2] = kv2;                                \
            *(uint4*)&Vs[buf_][vd2][vso2] = vv2;                                \
        } }

#define MFMA32(A_, B_, C_) __builtin_amdgcn_mfma_f32_32x32x16_bf16(A_, B_, C_, 0, 0, 0)

    f32x16 O1 = {}, O2 = {};
    const f32x16 z16 = {};

    int ktmax = 2 * qt + 1;                    // >= 1 always
    ATTN_LOAD();
    ATTN_STORE(0);
    ATTN_LOAD();
    __syncthreads();

    for (int kt = 0; kt <= ktmax; ++kt) {
        int buf = kt & 1;
        int k0  = kt * 64;
        if (kt + 1 <= ktmax) ATTN_STORE(buf ^ 1);
        if (kt + 2 <= ktmax) ATTN_LOAD();

#pragma unroll
        for (int kc = 0; kc < 2; ++kc) {
            int kbase = k0 + kc * 32;
            if (kbase <= q0w + 31) {           // wave-uniform active guard
                // ---- QK^T: A = K rows (kbase..+31), 3 dh-slices ----
                int krow = kc * 32 + l31;
                int ksw  = krow & 7;
                bf16x8 aK0 = *(const bf16x8*)&Ks[buf][krow][((0 + half) ^ ksw) * 8];
                bf16x8 aK1 = *(const bf16x8*)&Ks[buf][krow][((2 + half) ^ ksw) * 8];
                bf16x8 aK2 = *(const bf16x8*)&Ks[buf][krow][((4 + half) ^ ksw) * 8];

                __builtin_amdgcn_s_setprio(1);
                f32x16 s_;
                s_ = MFMA32(aK0, bQ0, z16);
                s_ = MFMA32(aK1, bQ1, s_);
                s_ = MFMA32(aK2, bQ2, s_);
                __builtin_amdgcn_s_setprio(0);

                // ---- causal mask (boundary tiles only) ----
                if (kbase + 31 > q0w) {
                    int qg = q0w + l31;
                    int kb = kbase + (hb ? 4 : 0);
#pragma unroll
                    for (int r = 0; r < 16; ++r) {
                        int kl = (r & 3) + 8 * (r >> 2);
                        if (kb + kl > qg) s_[r] = -1e30f;
                    }
                }

                // ---- exp2 (raw v_exp_f32) + pack ----
                unsigned int p0, p1, p2, p3, p4, p5, p6, p7;
                {
                    float e0 = EXP2(s_[0]),  e1 = EXP2(s_[1]);
                    float e2 = EXP2(s_[2]),  e3 = EXP2(s_[3]);
                    float e4 = EXP2(s_[4]),  e5 = EXP2(s_[5]);
                    float e6 = EXP2(s_[6]),  e7 = EXP2(s_[7]);
                    float e8 = EXP2(s_[8]),  e9 = EXP2(s_[9]);
                    float ea = EXP2(s_[10]), eb = EXP2(s_[11]);
                    float ec = EXP2(s_[12]), ed = EXP2(s_[13]);
                    float ee = EXP2(s_[14]), ef = EXP2(s_[15]);
                    p0 = pk2(e0, e1); p1 = pk2(e2, e3);
                    p2 = pk2(e4, e5); p3 = pk2(e6, e7);
                    p4 = pk2(e8, e9); p5 = pk2(ea, eb);
                    p6 = pk2(ec, ed); p7 = pk2(ee, ef);
                }

                // ---- half-exchange -> PV A-frags ----
                u32x4 F0w, F1w;
#if __has_builtin(__builtin_amdgcn_permlane32_swap)
                {
                    typedef unsigned int u32x2 __attribute__((ext_vector_type(2)));
                    u32x2 r0 = __builtin_amdgcn_permlane32_swap(p0, p2, false, false);
                    u32x2 r1 = __builtin_amdgcn_permlane32_swap(p1, p3, false, false);
                    u32x2 r2 = __builtin_amdgcn_permlane32_swap(p4, p6, false, false);
                    u32x2 r3 = __builtin_amdgcn_permlane32_swap(p5, p7, false, false);
                    F0w[0] = r0[0]; F0w[1] = r1[0]; F0w[2] = r0[1]; F0w[3] = r1[1];
                    F1w[0] = r2[0]; F1w[1] = r3[0]; F1w[2] = r2[1]; F1w[3] = r3[1];
                }
#else
                {
                    unsigned int sx0 = __shfl_xor(hb ? p0 : p2, 32, 64);
                    unsigned int sx1 = __shfl_xor(hb ? p1 : p3, 32, 64);
                    unsigned int sx2 = __shfl_xor(hb ? p4 : p6, 32, 64);
                    unsigned int sx3 = __shfl_xor(hb ? p5 : p7, 32, 64);
                    F0w[0] = hb ? sx0 : p0;  F0w[1] = hb ? sx1 : p1;
                    F0w[2] = hb ? p2  : sx0; F0w[3] = hb ? p3  : sx1;
                    F1w[0] = hb ? sx2 : p4;  F1w[1] = hb ? sx3 : p5;
                    F1w[2] = hb ? p6  : sx2; F1w[3] = hb ? p7  : sx3;
                }
#endif
                bf16x8 F0 = __builtin_bit_cast(bf16x8, F0w);
                bf16x8 F1 = __builtin_bit_cast(bf16x8, F1w);

                // ---- PV: B[col=d][k], d-tiles {0..31}, {32..63 (48=ones)} ----
                int vr0 = l31, vr1 = 32 + l31;
                int vw0 = vr0 & 7, vw1 = vr1 & 7;
                bf16x8 bV00 = *(const bf16x8*)&Vs[buf][vr0][((kc * 4 + 0 + half) ^ vw0) * 8];
                bf16x8 bV01 = *(const bf16x8*)&Vs[buf][vr1][((kc * 4 + 0 + half) ^ vw1) * 8];
                bf16x8 bV10 = *(const bf16x8*)&Vs[buf][vr0][((kc * 4 + 2 + half) ^ vw0) * 8];
                bf16x8 bV11 = *(const bf16x8*)&Vs[buf][vr1][((kc * 4 + 2 + half) ^ vw1) * 8];

                __builtin_amdgcn_s_setprio(1);
                O1 = MFMA32(F0, bV00, O1);
                O2 = MFMA32(F0, bV01, O2);
                O1 = MFMA32(F1, bV10, O1);
                O2 = MFMA32(F1, bV11, O2);
                __builtin_amdgcn_s_setprio(0);
            }
        }

        asm volatile("s_waitcnt lgkmcnt(0)" ::: "memory");
        __builtin_amdgcn_s_barrier();
        asm volatile("" ::: "memory");
    }

    // epilogue: lsum lives in O2 col 48 (lane l31==16 of own half)
    int lsrc = (lane & 32) + 16;
#pragma unroll
    for (int r = 0; r < 16; ++r) {
        float lden = __shfl(O2[r], lsrc, 64);
        float linv = 1.f / lden;
        int q = q0w + (r & 3) + 8 * (r >> 2) + (hb ? 4 : 0);
        size_t g = (rowbase + q) * DMODEL + h * DHEAD;
        Ao[g + l31] = __float2bfloat16(O1[r] * linv);
        if (l31 < 16)
            Ao[g + 32 + l31] = __float2bfloat16(O2[r] * linv);
    }
#undef ATTN_LOAD
#undef ATTN_STORE
#undef MFMA32
}

// ---------------- 4. LayerNorm (eps = 1e-3), wave-per-row, fp32 out ----------------
__global__ __launch_bounds__(256) void lnorm(
    const __hip_bfloat16* __restrict__ Ao,
    const float* __restrict__ gamma,
    const float* __restrict__ beta,
    float* __restrict__ out)
{
    int tid = threadIdx.x;
    int wv  = tid >> 6, ln = tid & 63;
    int row = blockIdx.x * 4 + wv;
    size_t base = (size_t)row * DMODEL + ln * 4;

    ushort4 u0 = *(const ushort4*)(Ao + base);
    ushort4 u1 = *(const ushort4*)(Ao + base + 256);
    ushort4 u2 = *(const ushort4*)(Ao + base + 512);
    float x0, x1, x2, x3, x4, x5, x6, x7, x8, x9, xa, xb;
    { unsigned int v = (unsigned int)u0.x << 16; __builtin_memcpy(&x0, &v, 4); }
    { unsigned int v = (unsigned int)u0.y << 16; __builtin_memcpy(&x1, &v, 4); }
    { unsigned int v = (unsigned int)u0.z << 16; __builtin_memcpy(&x2, &v, 4); }
    { unsigned int v = (unsigned int)u0.w << 16; __builtin_memcpy(&x3, &v, 4); }
    { unsigned int v = (unsigned int)u1.x << 16; __builtin_memcpy(&x4, &v, 4); }
    { unsigned int v = (unsigned int)u1.y << 16; __builtin_memcpy(&x5, &v, 4); }
    { unsigned int v = (unsigned int)u1.z << 16; __builtin_memcpy(&x6, &v, 4); }
    { unsigned int v = (unsigned int)u1.w << 16; __builtin_memcpy(&x7, &v, 4); }
    { unsigned int v = (unsigned int)u2.x << 16; __builtin_memcpy(&x8, &v, 4); }
    { unsigned int v = (unsigned int)u2.y << 16; __builtin_memcpy(&x9, &v, 4); }
    { unsigned int v = (unsigned int)u2.z << 16; __builtin_memcpy(&xa, &v, 4); }
    { unsigned int v = (unsigned int)u2.w << 16; __builtin_memcpy(&xb, &v, 4); }

    float s = ((x0 + x1) + (x2 + x3)) + ((x4 + x5) + (x6 + x7)) + ((x8 + x9) + (xa + xb));
    float q = ((x0*x0 + x1*x1) + (x2*x2 + x3*x3)) + ((x4*x4 + x5*x5) + (x6*x6 + x7*x7))
            + ((x8*x8 + x9*x9) + (xa*xa + xb*xb));
#pragma unroll
    for (int m = 32; m >= 1; m >>= 1) {
        s += __shfl_xor(s, m, 64);
        q += __shfl_xor(q, m, 64);
    }
    float mu  = s * (1.f / 768.f);
    float var = q * (1.f / 768.f) - mu * mu;
    float rstd = rsqrtf(var + 1e-3f);

    float4 g0 = *(const float4*)(gamma + ln * 4);
    float4 g1 = *(const float4*)(gamma + ln * 4 + 256);
    float4 g2 = *(const float4*)(gamma + ln * 4 + 512);
    float4 e0 = *(const float4*)(beta + ln * 4);
    float4 e1 = *(const float4*)(beta + ln * 4 + 256);
    float4 e2 = *(const float4*)(beta + ln * 4 + 512);
    float4 o0, o1, o2;
    o0.x = (x0 - mu) * rstd * g0.x + e0.x;
    o0.y = (x1 - mu) * rstd * g0.y + e0.y;
    o0.z = (x2 - mu) * rstd * g0.z + e0.z;
    o0.w = (x3 - mu) * rstd * g0.w + e0.w;
    o1.x = (x4 - mu) * rstd * g1.x + e1.x;
    o1.y = (x5 - mu) * rstd * g1.y + e1.y;
    o1.z = (x6 - mu) * rstd * g1.z + e1.z;
    o1.w = (x7 - mu) * rstd * g1.w + e1.w;
    o2.x = (x8 - mu) * rstd * g2.x + e2.x;
    o2.y = (x9 - mu) * rstd * g2.y + e2.y;
    o2.z = (xa - mu) * rstd * g2.z + e2.z;
    o2.w = (xb - mu) * rstd * g2.w + e2.w;
    *(float4*)(out + base)       = o0;
    *(float4*)(out + base + 256) = o1;
    *(float4*)(out + base + 512) = o2;
}

extern "C" void kernel_launch(void* const* d_in, const int* in_sizes, int n_in,
                              void* d_out, int out_size, void* d_ws, size_t ws_size,
                              hipStream_t stream) {
    const float* q     = (const float*)d_in[0];
    const float* k     = (const float*)d_in[1];
    const float* v     = (const float*)d_in[2];
    const float* Wq    = (const float*)d_in[3];
    const float* bq    = (const float*)d_in[4];
    const float* Wk    = (const float*)d_in[5];
    const float* bk    = (const float*)d_in[6];
    const float* Wv    = (const float*)d_in[7];
    const float* bv    = (const float*)d_in[8];
    const float* gamma = (const float*)d_in[9];
    const float* beta  = (const float*)d_in[10];

    char* basep = (char*)d_ws;
    __hip_bfloat16* Wt = (__hip_bfloat16*)basep;
    __hip_bfloat16* Qr = (__hip_bfloat16*)(basep + 3538944);
    __hip_bfloat16* Kr = Qr + (size_t)NROWS * DMODEL;
    __hip_bfloat16* Vt = Kr + (size_t)NROWS * DMODEL;
    __hip_bfloat16* Ao = Vt + (size_t)NROWS * DMODEL;
    float* out = (float*)d_out;

    __hip_bfloat16* Xbq = (__hip_bfloat16*)d_out;
    __hip_bfloat16* Xbk = Xbq + (size_t)NROWS * DMODEL;
    __hip_bfloat16* Xbv = Ao;

    hipLaunchKernelGGL(prep, dim3(10944), dim3(256), 0, stream,
                       Wq, Wk, Wv, q, k, v, Wt, Xbq, Xbk, Xbv);
    hipLaunchKernelGGL(qkv_proj, dim3(1152), dim3(256), 0, stream,
                       Xbq, Xbk, Xbv, Wt, bq, bk, bv, Qr, Kr, Vt);
    hipLaunchKernelGGL(attn, dim3(1024), dim3(256), 0, stream, Qr, Kr, Vt, Ao);
    hipLaunchKernelGGL(lnorm, dim3(2048), dim3(256), 0, stream, Ao, gamma, beta, out);
}